// Round 1
// baseline (372.601 us; speedup 1.0000x reference)
//
#include <hip/hip_runtime.h>

#define DEVI __device__ __forceinline__

typedef __attribute__((ext_vector_type(4))) float f32x4;
typedef __attribute__((ext_vector_type(8))) short s16x8;
typedef __attribute__((ext_vector_type(4))) short s16x4;

#if __has_builtin(__builtin_amdgcn_exp2f)
#define EXP2F __builtin_amdgcn_exp2f
#else
#define EXP2F exp2f
#endif

DEVI ushort f2bf(float f) {
  unsigned u = __builtin_bit_cast(unsigned, f);
  u += 0x7fffu + ((u >> 16) & 1u);
  return (ushort)(u >> 16);
}

DEVI void gload_lds16(const void* g, void* l) {
  typedef const unsigned int GlobU __attribute__((address_space(1)));
  typedef unsigned int LdsU __attribute__((address_space(3)));
  __builtin_amdgcn_global_load_lds((GlobU*)g, (LdsU*)l, 16, 0, 0);
}

// ---------------- elementwise fp32 -> bf16 cast ----------------
__global__ __launch_bounds__(256) void cast_bf16_kernel(
    const float4* __restrict__ in, ushort4* __restrict__ out, int n4) {
  int i = blockIdx.x * 256 + threadIdx.x;
  if (i >= n4) return;
  float4 v = in[i];
  ushort4 o;
  o.x = f2bf(v.x); o.y = f2bf(v.y); o.z = f2bf(v.z); o.w = f2bf(v.w);
  out[i] = o;
}

// ---------------- transpose + cast: in fp32 [R][C] -> out bf16 [C][R] ----------------
__global__ __launch_bounds__(256) void transpose_cast_kernel(
    const float* __restrict__ in, ushort* __restrict__ out, int R, int C) {
  __shared__ ushort tile[64][65];
  int cb = blockIdx.x * 64, rb = blockIdx.y * 64;
  int t = threadIdx.x;
  int c4 = (t & 15) * 4, r0 = t >> 4;
#pragma unroll
  for (int i = 0; i < 4; i++) {
    int r = r0 + i * 16;
    float4 v = *(const float4*)(in + (size_t)(rb + r) * C + cb + c4);
    tile[r][c4 + 0] = f2bf(v.x);
    tile[r][c4 + 1] = f2bf(v.y);
    tile[r][c4 + 2] = f2bf(v.z);
    tile[r][c4 + 3] = f2bf(v.w);
  }
  __syncthreads();
#pragma unroll
  for (int i = 0; i < 4; i++) {
    int rr = r0 + i * 16;
    ushort4 o;
    o.x = tile[c4 + 0][rr]; o.y = tile[c4 + 1][rr];
    o.z = tile[c4 + 2][rr]; o.w = tile[c4 + 3][rr];
    *(ushort4*)(out + (size_t)(cb + rr) * R + rb + c4) = o;
  }
}

// ---------------- bf16 GEMM: C[M][N] = A[M][K] @ Bt[N][K]^T ----------------
// MODE 0: Q epilogue  (bf16 [b][h][n][d], scaled by 0.125*log2e)
// MODE 1: KV epilogue (K bf16 [b][h][m][d]; V bf16 transposed [b][h][d][m])
// MODE 2: out epilogue (fp32 [M][N] + bias)
template <int MODE>
__global__ __launch_bounds__(256, 2) void gemm_bt(
    const ushort* __restrict__ A, const ushort* __restrict__ Bt,
    void* __restrict__ C0, void* __restrict__ C1,
    const float* __restrict__ bias, int N, int K) {
  __shared__ ushort As[128 * 32];
  __shared__ ushort Bs[128 * 32];
  const int tid = threadIdx.x;
  const int lane = tid & 63, wave = tid >> 6;
  const int quad = lane >> 4, ln = lane & 15;
  const int rowbase = blockIdx.y * 128, colbase = blockIdx.x * 128;
  const int wrow = (wave >> 1) * 64, wcol = (wave & 1) * 64;
  f32x4 acc[4][4] = {};

  for (int k0 = 0; k0 < K; k0 += 32) {
    __syncthreads();
#pragma unroll
    for (int i = 0; i < 2; i++) {
      int f = i * 256 + tid;
      int r = f >> 2;
      int c = (f & 3) ^ (r & 3);
      gload_lds16(A + (size_t)(rowbase + r) * K + (k0 + c * 8),
                  (char*)As + (size_t)(i * 256 + wave * 64) * 16);
      gload_lds16(Bt + (size_t)(colbase + r) * K + (k0 + c * 8),
                  (char*)Bs + (size_t)(i * 256 + wave * 64) * 16);
    }
    __syncthreads();
    s16x8 a[4], b[4];
#pragma unroll
    for (int mt = 0; mt < 4; mt++) {
      int r = wrow + mt * 16 + ln;
      a[mt] = *(const s16x8*)(As + ((size_t)r * 4 + (quad ^ (r & 3))) * 8);
    }
#pragma unroll
    for (int nt = 0; nt < 4; nt++) {
      int r = wcol + nt * 16 + ln;
      b[nt] = *(const s16x8*)(Bs + ((size_t)r * 4 + (quad ^ (r & 3))) * 8);
    }
#pragma unroll
    for (int mt = 0; mt < 4; mt++)
#pragma unroll
      for (int nt = 0; nt < 4; nt++)
        acc[mt][nt] = __builtin_amdgcn_mfma_f32_16x16x32_bf16(a[mt], b[nt], acc[mt][nt], 0, 0, 0);
  }

  if constexpr (MODE == 0) {
    const float qscale = 0.18033688011112042f;  // 1/8 * log2(e)
    ushort* Qo = (ushort*)C0;
#pragma unroll
    for (int nt = 0; nt < 4; nt++) {
      int col = colbase + wcol + nt * 16 + ln;
      int h = col >> 6, d = col & 63;
#pragma unroll
      for (int mt = 0; mt < 4; mt++) {
        int row = rowbase + wrow + mt * 16 + quad * 4;
#pragma unroll
        for (int r = 0; r < 4; r++) {
          int rr = row + r;
          int bb = rr >> 11, n = rr & 2047;
          Qo[(((size_t)bb * 16 + h) * 2048 + n) * 64 + d] = f2bf(acc[mt][nt][r] * qscale);
        }
      }
    }
  } else if constexpr (MODE == 1) {
    ushort* Ko = (ushort*)C0;
    ushort* Vo = (ushort*)C1;
    bool isK = (colbase < 1024);
#pragma unroll
    for (int nt = 0; nt < 4; nt++) {
      int col = colbase + wcol + nt * 16 + ln;
#pragma unroll
      for (int mt = 0; mt < 4; mt++) {
        int row = rowbase + wrow + mt * 16 + quad * 4;
        int bb = row >> 11, m = row & 2047;
        if (isK) {
          int h = col >> 6, d = col & 63;
#pragma unroll
          for (int r = 0; r < 4; r++)
            Ko[(((size_t)bb * 16 + h) * 2048 + (m + r)) * 64 + d] = f2bf(acc[mt][nt][r]);
        } else {
          int c2 = col - 1024;
          int h = c2 >> 6, d = c2 & 63;
          s16x4 pk;
#pragma unroll
          for (int r = 0; r < 4; r++) pk[r] = (short)f2bf(acc[mt][nt][r]);
          *(s16x4*)(Vo + (((size_t)bb * 16 + h) * 64 + d) * 2048 + m) = pk;
        }
      }
    }
  } else {
    float* C = (float*)C0;
#pragma unroll
    for (int nt = 0; nt < 4; nt++) {
      int col = colbase + wcol + nt * 16 + ln;
      float bv = bias[col];
#pragma unroll
      for (int mt = 0; mt < 4; mt++) {
        int row = rowbase + wrow + mt * 16 + quad * 4;
#pragma unroll
        for (int r = 0; r < 4; r++)
          C[(size_t)(row + r) * N + col] = acc[mt][nt][r] + bv;
      }
    }
  }
}

// ---------------- flash attention ----------------
// S^T = K @ Q^T formulation; Q pre-scaled by 0.125*log2e.
// Q: bf16 [b][h][n][64]; K: bf16 [b][h][m][64]; VT: bf16 [b][h][64][m]
// O: bf16 [b][n][h*64]
__global__ __launch_bounds__(256, 2) void attn_kernel(
    const ushort* __restrict__ Q, const ushort* __restrict__ K,
    const ushort* __restrict__ VT, const float* __restrict__ xmask,
    const float* __restrict__ cmask, ushort* __restrict__ O) {
  __shared__ ushort Ks[64 * 64];
  __shared__ ushort Vs[64 * 64];
  __shared__ ushort Ps[4 * 64 * 64];  // per-wave [64 q][64 key] bf16, 8B-chunk swizzled
  const int tid = threadIdx.x, lane = tid & 63, wave = tid >> 6;
  const int quad = lane >> 4, ln = lane & 15;
  const int bid = blockIdx.x;
  const int qb = bid & 7, h = (bid >> 3) & 15, b = bid >> 7;
  const size_t bh = (size_t)b * 16 + h;
  const ushort* Qbh = Q + bh * (2048 * 64);
  const ushort* Kbh = K + bh * (2048 * 64);
  const ushort* Vbh = VT + bh * (64 * 2048);
  const int q0 = qb * 256 + wave * 64;

  // Q fragments (B-operand: n=q=ln, k=d=quad*8+j (+32*kc)), held in registers
  s16x8 qf[4][2];
#pragma unroll
  for (int qt = 0; qt < 4; qt++)
#pragma unroll
    for (int kc = 0; kc < 2; kc++)
      qf[qt][kc] = *(const s16x8*)(Qbh + (size_t)(q0 + qt * 16 + ln) * 64 + kc * 32 + quad * 8);

  float xm[4];
#pragma unroll
  for (int qt = 0; qt < 4; qt++) xm[qt] = xmask[b * 2048 + q0 + qt * 16 + ln];

  f32x4 o[4][4] = {};  // o[dt][qt]: rows d = dt*16+quad*4+r, col q = ln
  float mrun[4], lrun[4];
#pragma unroll
  for (int qt = 0; qt < 4; qt++) { mrun[qt] = -1e30f; lrun[qt] = 0.f; }

  for (int kb = 0; kb < 32; kb++) {
    const int m0 = kb * 64;
    __syncthreads();
#pragma unroll
    for (int i = 0; i < 2; i++) {
      int f = i * 256 + tid;
      int r = f >> 3;
      int c = (f & 7) ^ (r & 7);
      gload_lds16(Kbh + (size_t)(m0 + r) * 64 + c * 8,
                  (char*)Ks + (size_t)(i * 256 + wave * 64) * 16);
      gload_lds16(Vbh + (size_t)r * 2048 + (m0 + c * 8),
                  (char*)Vs + (size_t)(i * 256 + wave * 64) * 16);
    }
    float4 cm4[4];
#pragma unroll
    for (int kt = 0; kt < 4; kt++)
      cm4[kt] = *(const float4*)(cmask + b * 2048 + m0 + kt * 16 + quad * 4);
    __syncthreads();

    // S^T: s[kt][qt], rows = keys (kt*16+quad*4+reg), col = q (ln)
    f32x4 s[4][4] = {};
#pragma unroll
    for (int kc = 0; kc < 2; kc++) {
#pragma unroll
      for (int kt = 0; kt < 4; kt++) {
        int r = kt * 16 + ln;
        s16x8 ka = *(const s16x8*)(Ks + ((size_t)r * 8 + ((kc * 4 + quad) ^ (r & 7))) * 8);
#pragma unroll
        for (int qt = 0; qt < 4; qt++)
          s[kt][qt] = __builtin_amdgcn_mfma_f32_16x16x32_bf16(ka, qf[qt][kc], s[kt][qt], 0, 0, 0);
      }
    }

    // online softmax per qt (stats per q: reduce regs + shfl over quads)
#pragma unroll
    for (int qt = 0; qt < 4; qt++) {
      float vmax = -1e30f;
#pragma unroll
      for (int kt = 0; kt < 4; kt++)
#pragma unroll
        for (int r = 0; r < 4; r++) vmax = fmaxf(vmax, s[kt][qt][r]);
      vmax = fmaxf(vmax, __shfl_xor(vmax, 16, 64));
      vmax = fmaxf(vmax, __shfl_xor(vmax, 32, 64));
      float mnew = fmaxf(mrun[qt], vmax);
      float alpha = EXP2F(mrun[qt] - mnew);
      mrun[qt] = mnew;
      float rs = 0.f;
      int qrow = qt * 16 + ln;
      ushort* pb = Ps + wave * 4096 + qrow * 64;
#pragma unroll
      for (int kt = 0; kt < 4; kt++) {
        float cmv[4] = {cm4[kt].x, cm4[kt].y, cm4[kt].z, cm4[kt].w};
        s16x4 pk;
#pragma unroll
        for (int r = 0; r < 4; r++) {
          float p = EXP2F(s[kt][qt][r] - mnew) * cmv[r];
          rs += p;
          pk[r] = (short)f2bf(p);
        }
        *(s16x4*)(pb + ((kt * 4 + quad) ^ (qrow & 14)) * 4) = pk;
      }
      rs += __shfl_xor(rs, 16, 64);
      rs += __shfl_xor(rs, 32, 64);
      lrun[qt] = lrun[qt] * alpha + rs;
#pragma unroll
      for (int dt = 0; dt < 4; dt++)
#pragma unroll
        for (int r = 0; r < 4; r++) o[dt][qt][r] *= alpha;
    }

    // PV: o[dt][qt] += V^T(frag A) @ P^T(frag B)
#pragma unroll
    for (int kc = 0; kc < 2; kc++) {
      s16x8 pf[4];
#pragma unroll
      for (int qt = 0; qt < 4; qt++) {
        int qrow = qt * 16 + ln;
        pf[qt] = *(const s16x8*)(Ps + wave * 4096 + qrow * 64 +
                                 ((kc * 8 + quad * 2) ^ (qrow & 14)) * 4);
      }
#pragma unroll
      for (int dt = 0; dt < 4; dt++) {
        int r = dt * 16 + ln;
        s16x8 va = *(const s16x8*)(Vs + ((size_t)r * 8 + ((kc * 4 + quad) ^ (r & 7))) * 8);
#pragma unroll
        for (int qt = 0; qt < 4; qt++)
          o[dt][qt] = __builtin_amdgcn_mfma_f32_16x16x32_bf16(va, pf[qt], o[dt][qt], 0, 0, 0);
      }
    }
  }

  // normalize + store O [b][n][h*64+d]
#pragma unroll
  for (int qt = 0; qt < 4; qt++) {
    float inv = (xm[qt] != 0.f && lrun[qt] > 0.f) ? (1.f / lrun[qt]) : 0.f;
    int n = q0 + qt * 16 + ln;
    ushort* ob = O + ((size_t)(b * 2048 + n) * 16 + h) * 64;
#pragma unroll
    for (int dt = 0; dt < 4; dt++) {
      s16x4 pk;
#pragma unroll
      for (int r = 0; r < 4; r++) pk[r] = (short)f2bf(o[dt][qt][r] * inv);
      *(s16x4*)(ob + dt * 16 + quad * 4) = pk;
    }
  }
}

// ---------------- host launcher ----------------
extern "C" void kernel_launch(void* const* d_in, const int* in_sizes, int n_in,
                              void* d_out, int out_size, void* d_ws, size_t ws_size,
                              hipStream_t stream) {
  const float* x   = (const float*)d_in[0];
  const float* ctx = (const float*)d_in[1];
  const float* xm  = (const float*)d_in[2];
  const float* cm  = (const float*)d_in[3];
  const float* Wq  = (const float*)d_in[4];
  const float* Wkv = (const float*)d_in[5];
  const float* Wo  = (const float*)d_in[6];
  const float* bo  = (const float*)d_in[7];

  char* ws = (char*)d_ws;
  const size_t MB = 1024 * 1024;
  ushort* xb   = (ushort*)(ws + 0);         // 16MB (x bf16; reused as O after GEMM1)
  ushort* cb   = (ushort*)(ws + 16 * MB);   // 16MB (context bf16)
  ushort* WqT  = (ushort*)(ws + 32 * MB);   // 2MB
  ushort* WkvT = (ushort*)(ws + 34 * MB);   // 4MB
  ushort* WoT  = (ushort*)(ws + 38 * MB);   // 2MB
  ushort* Qb   = (ushort*)(ws + 40 * MB);   // 16MB
  ushort* Kb   = (ushort*)(ws + 56 * MB);   // 16MB
  ushort* VTb  = (ushort*)(ws + 72 * MB);   // 16MB
  ushort* Ob   = xb;                        // alias: x bf16 is dead after GEMM1

  cast_bf16_kernel<<<8192, 256, 0, stream>>>((const float4*)x, (ushort4*)xb, 2097152);
  cast_bf16_kernel<<<8192, 256, 0, stream>>>((const float4*)ctx, (ushort4*)cb, 2097152);
  transpose_cast_kernel<<<dim3(16, 16), 256, 0, stream>>>(Wq, WqT, 1024, 1024);
  transpose_cast_kernel<<<dim3(32, 16), 256, 0, stream>>>(Wkv, WkvT, 1024, 2048);
  transpose_cast_kernel<<<dim3(16, 16), 256, 0, stream>>>(Wo, WoT, 1024, 1024);

  gemm_bt<0><<<dim3(8, 64), 256, 0, stream>>>(xb, WqT, (void*)Qb, nullptr, nullptr, 1024, 1024);
  gemm_bt<1><<<dim3(16, 64), 256, 0, stream>>>(cb, WkvT, (void*)Kb, (void*)VTb, nullptr, 2048, 1024);
  attn_kernel<<<512, 256, 0, stream>>>(Qb, Kb, VTb, xm, cm, Ob);
  gemm_bt<2><<<dim3(8, 64), 256, 0, stream>>>(Ob, WoT, d_out, nullptr, bo, 1024, 1024);
}

// Round 2
// 340.104 us; speedup vs baseline: 1.0956x; 1.0956x over previous
//
#include <hip/hip_runtime.h>

#define DEVI __device__ __forceinline__

typedef __attribute__((ext_vector_type(4))) float f32x4;
typedef __attribute__((ext_vector_type(8))) short s16x8;
typedef __attribute__((ext_vector_type(8))) _Float16 f16x8;
typedef __attribute__((ext_vector_type(2))) _Float16 f16x2;

#if __has_builtin(__builtin_amdgcn_exp2f)
#define EXP2F __builtin_amdgcn_exp2f
#else
#define EXP2F exp2f
#endif

DEVI ushort f2h(float f) {  // RNE scalar convert (v_cvt_f16_f32)
  _Float16 h = (_Float16)f;
  return __builtin_bit_cast(ushort, h);
}

DEVI unsigned pkrtz(float a, float b) {  // v_cvt_pkrtz_f16_f32: 2 converts, 1 instr
  return __builtin_bit_cast(unsigned, __builtin_amdgcn_cvt_pkrtz(a, b));
}

DEVI float dot2acc(unsigned pk, float acc) {
#if __has_builtin(__builtin_amdgcn_fdot2)
  f16x2 one2 = {(_Float16)1.0f, (_Float16)1.0f};
  return __builtin_amdgcn_fdot2(__builtin_bit_cast(f16x2, pk), one2, acc, false);
#else
  f16x2 v = __builtin_bit_cast(f16x2, pk);
  return acc + (float)v[0] + (float)v[1];
#endif
}

DEVI void gload_lds16(const void* g, void* l) {
  typedef const unsigned int GlobU __attribute__((address_space(1)));
  typedef unsigned int LdsU __attribute__((address_space(3)));
  __builtin_amdgcn_global_load_lds((GlobU*)g, (LdsU*)l, 16, 0, 0);
}

// ---------------- fused fp32 -> fp16 cast of x and context ----------------
__global__ __launch_bounds__(256) void cast_f16_kernel(
    const float4* __restrict__ x, const float4* __restrict__ ctx,
    ushort4* __restrict__ xo, ushort4* __restrict__ co) {
  int i = blockIdx.x * 256 + threadIdx.x;
  const float4* src;
  ushort4* dst;
  int j;
  if (i < 2097152) { src = x; dst = xo; j = i; }
  else             { src = ctx; dst = co; j = i - 2097152; }
  float4 v = src[j];
  ushort4 o;
  o.x = f2h(v.x); o.y = f2h(v.y); o.z = f2h(v.z); o.w = f2h(v.w);
  dst[j] = o;
}

// ---------------- fused transpose+cast of the 3 weights (all R=1024 rows) ----------------
__global__ __launch_bounds__(256) void transpose_cast_kernel(
    const float* __restrict__ Wq, const float* __restrict__ Wkv,
    const float* __restrict__ Wo, ushort* __restrict__ WqT,
    ushort* __restrict__ WkvT, ushort* __restrict__ WoT) {
  __shared__ ushort tile[64][65];
  int bx = blockIdx.x;
  const float* in; ushort* out; int C, cb;
  if (bx < 16)      { in = Wq;  out = WqT;  C = 1024; cb = bx * 64; }
  else if (bx < 48) { in = Wkv; out = WkvT; C = 2048; cb = (bx - 16) * 64; }
  else              { in = Wo;  out = WoT;  C = 1024; cb = (bx - 48) * 64; }
  const int R = 1024;
  int rb = blockIdx.y * 64;
  int t = threadIdx.x;
  int c4 = (t & 15) * 4, r0 = t >> 4;
#pragma unroll
  for (int i = 0; i < 4; i++) {
    int r = r0 + i * 16;
    float4 v = *(const float4*)(in + (size_t)(rb + r) * C + cb + c4);
    tile[r][c4 + 0] = f2h(v.x);
    tile[r][c4 + 1] = f2h(v.y);
    tile[r][c4 + 2] = f2h(v.z);
    tile[r][c4 + 3] = f2h(v.w);
  }
  __syncthreads();
#pragma unroll
  for (int i = 0; i < 4; i++) {
    int rr = r0 + i * 16;
    ushort4 o;
    o.x = tile[c4 + 0][rr]; o.y = tile[c4 + 1][rr];
    o.z = tile[c4 + 2][rr]; o.w = tile[c4 + 3][rr];
    *(ushort4*)(out + (size_t)(cb + rr) * R + rb + c4) = o;
  }
}

// ---------------- shared fp16 GEMM core: acc += A[M][K] @ Bt[N][K]^T tile ----------------
DEVI void gemm_core(const ushort* __restrict__ A, const ushort* __restrict__ Bt,
                    int K, int rowbase, int colbase, int tid,
                    ushort* As, ushort* Bs, f32x4 acc[4][4]) {
  const int lane = tid & 63, wave = tid >> 6;
  const int quad = lane >> 4, ln = lane & 15;
  const int wrow = (wave >> 1) * 64, wcol = (wave & 1) * 64;
  for (int k0 = 0; k0 < K; k0 += 32) {
    __syncthreads();
#pragma unroll
    for (int i = 0; i < 2; i++) {
      int f = i * 256 + tid;
      int r = f >> 2;
      int c = (f & 3) ^ (r & 3);
      gload_lds16(A + (size_t)(rowbase + r) * K + (k0 + c * 8),
                  (char*)As + (size_t)(i * 256 + wave * 64) * 16);
      gload_lds16(Bt + (size_t)(colbase + r) * K + (k0 + c * 8),
                  (char*)Bs + (size_t)(i * 256 + wave * 64) * 16);
    }
    __syncthreads();
    f16x8 a[4], b[4];
#pragma unroll
    for (int mt = 0; mt < 4; mt++) {
      int r = wrow + mt * 16 + ln;
      a[mt] = *(const f16x8*)(As + ((size_t)r * 4 + (quad ^ (r & 3))) * 8);
    }
#pragma unroll
    for (int nt = 0; nt < 4; nt++) {
      int r = wcol + nt * 16 + ln;
      b[nt] = *(const f16x8*)(Bs + ((size_t)r * 4 + (quad ^ (r & 3))) * 8);
    }
#pragma unroll
    for (int mt = 0; mt < 4; mt++)
#pragma unroll
      for (int nt = 0; nt < 4; nt++)
        acc[mt][nt] = __builtin_amdgcn_mfma_f32_16x16x32_f16(a[mt], b[nt], acc[mt][nt], 0, 0, 0);
  }
}

// ---------------- fused Q + KV projection GEMM ----------------
// bx<8: Q = x@Wq, scaled, -> fp16 [b][h][n][64]
// bx>=8: KV = ctx@Wkv -> K fp16 [b][h][m][64], V fp16 transposed [b][h][64][m]
__global__ __launch_bounds__(256, 2) void qkv_gemm(
    const ushort* __restrict__ xb, const ushort* __restrict__ cb,
    const ushort* __restrict__ WqT, const ushort* __restrict__ WkvT,
    ushort* __restrict__ Qo, ushort* __restrict__ Ko, ushort* __restrict__ Vo) {
  __shared__ ushort As[128 * 32];
  __shared__ ushort Bs[128 * 32];
  const int tid = threadIdx.x;
  const int lane = tid & 63, wave = tid >> 6;
  const int quad = lane >> 4, ln = lane & 15;
  const int bx = blockIdx.x;
  const bool isQ = bx < 8;
  const int colbase = (isQ ? bx : bx - 8) * 128;
  const int rowbase = blockIdx.y * 128;
  const int wrow = (wave >> 1) * 64, wcol = (wave & 1) * 64;
  f32x4 acc[4][4] = {};
  gemm_core(isQ ? xb : cb, isQ ? WqT : WkvT, 1024, rowbase, colbase, tid, As, Bs, acc);

  if (isQ) {
    const float qscale = 0.18033688011112042f;  // 1/8 * log2(e)
#pragma unroll
    for (int nt = 0; nt < 4; nt++) {
      int col = colbase + wcol + nt * 16 + ln;
      int h = col >> 6, d = col & 63;
#pragma unroll
      for (int mt = 0; mt < 4; mt++) {
        int row = rowbase + wrow + mt * 16 + quad * 4;
#pragma unroll
        for (int r = 0; r < 4; r++) {
          int rr = row + r;
          int bb = rr >> 11, n = rr & 2047;
          Qo[(((size_t)bb * 16 + h) * 2048 + n) * 64 + d] = f2h(acc[mt][nt][r] * qscale);
        }
      }
    }
  } else {
    bool isK = (colbase < 1024);
#pragma unroll
    for (int nt = 0; nt < 4; nt++) {
      int col = colbase + wcol + nt * 16 + ln;
#pragma unroll
      for (int mt = 0; mt < 4; mt++) {
        int row = rowbase + wrow + mt * 16 + quad * 4;
        int bb = row >> 11, m = row & 2047;
        if (isK) {
          int h = col >> 6, d = col & 63;
#pragma unroll
          for (int r = 0; r < 4; r++)
            Ko[(((size_t)bb * 16 + h) * 2048 + (m + r)) * 64 + d] = f2h(acc[mt][nt][r]);
        } else {
          int c2 = col - 1024;
          int h = c2 >> 6, d = c2 & 63;
          uint2 pv;
          pv.x = pkrtz(acc[mt][nt][0], acc[mt][nt][1]);
          pv.y = pkrtz(acc[mt][nt][2], acc[mt][nt][3]);
          *(uint2*)(Vo + (((size_t)bb * 16 + h) * 64 + d) * 2048 + m) = pv;
        }
      }
    }
  }
}

// ---------------- out projection: fp32 [M][N] = A @ WoT^T + bias ----------------
__global__ __launch_bounds__(256, 2) void out_gemm(
    const ushort* __restrict__ A, const ushort* __restrict__ Bt,
    float* __restrict__ C, const float* __restrict__ bias) {
  __shared__ ushort As[128 * 32];
  __shared__ ushort Bs[128 * 32];
  const int tid = threadIdx.x;
  const int lane = tid & 63, wave = tid >> 6;
  const int quad = lane >> 4, ln = lane & 15;
  const int colbase = blockIdx.x * 128, rowbase = blockIdx.y * 128;
  const int wrow = (wave >> 1) * 64, wcol = (wave & 1) * 64;
  f32x4 acc[4][4] = {};
  gemm_core(A, Bt, 1024, rowbase, colbase, tid, As, Bs, acc);
#pragma unroll
  for (int nt = 0; nt < 4; nt++) {
    int col = colbase + wcol + nt * 16 + ln;
    float bv = bias[col];
#pragma unroll
    for (int mt = 0; mt < 4; mt++) {
      int row = rowbase + wrow + mt * 16 + quad * 4;
#pragma unroll
      for (int r = 0; r < 4; r++)
        C[(size_t)(row + r) * 1024 + col] = acc[mt][nt][r] + bv;
    }
  }
}

// ---------------- flash attention, fixed-max softmax ----------------
// S^T = K @ Q^T; Q pre-scaled by 0.125*log2e; p = exp2(s + maskbias), no running max.
// Q: fp16 [b][h][n][64]; K: fp16 [b][h][m][64]; VT: fp16 [b][h][64][m]; O: fp16 [b][n][h*64]
__global__ __launch_bounds__(256, 2) void attn_kernel(
    const ushort* __restrict__ Q, const ushort* __restrict__ K,
    const ushort* __restrict__ VT, const float* __restrict__ xmask,
    const float* __restrict__ cmask, ushort* __restrict__ O) {
  __shared__ ushort Ks[64 * 64];
  __shared__ ushort Vs[64 * 64];
  __shared__ ushort Ps[4 * 64 * 72];  // per-wave rows of 64 keys, stride 72 (144B: bank-spread, 16B-aligned)
  const int tid = threadIdx.x, lane = tid & 63, wave = tid >> 6;
  const int quad = lane >> 4, ln = lane & 15;
  const int bid = blockIdx.x;
  const int qb = bid & 7, h = (bid >> 3) & 15, b = bid >> 7;
  const size_t bh = (size_t)b * 16 + h;
  const ushort* Qbh = Q + bh * (2048 * 64);
  const ushort* Kbh = K + bh * (2048 * 64);
  const ushort* Vbh = VT + bh * (64 * 2048);
  const int q0 = qb * 256 + wave * 64;

  // Q fragments (B-operand: n=q=ln, k=d=quad*8+j (+32*kc)), held in registers
  f16x8 qf[4][2];
#pragma unroll
  for (int qt = 0; qt < 4; qt++)
#pragma unroll
    for (int kc = 0; kc < 2; kc++)
      qf[qt][kc] = *(const f16x8*)(Qbh + (size_t)(q0 + qt * 16 + ln) * 64 + kc * 32 + quad * 8);

  float xm[4];
#pragma unroll
  for (int qt = 0; qt < 4; qt++) xm[qt] = xmask[b * 2048 + q0 + qt * 16 + ln];

  f32x4 o[4][4] = {};  // o[dt][qt]: rows d = dt*16+quad*4+r, col q = ln
  float lrun[4] = {0.f, 0.f, 0.f, 0.f};

  for (int kb = 0; kb < 32; kb++) {
    const int m0 = kb * 64;
    __syncthreads();
#pragma unroll
    for (int i = 0; i < 2; i++) {
      int f = i * 256 + tid;
      int r = f >> 3;
      int c = (f & 7) ^ (r & 7);
      gload_lds16(Kbh + (size_t)(m0 + r) * 64 + c * 8,
                  (char*)Ks + (size_t)(i * 256 + wave * 64) * 16);
      gload_lds16(Vbh + (size_t)r * 2048 + (m0 + c * 8),
                  (char*)Vs + (size_t)(i * 256 + wave * 64) * 16);
    }
    // mask bias for this wave's key rows: 0 if valid, -3e4 if masked (exp2 -> exact 0)
    f32x4 bias4[4];
#pragma unroll
    for (int kt = 0; kt < 4; kt++) {
      float4 cm = *(const float4*)(cmask + b * 2048 + m0 + kt * 16 + quad * 4);
      bias4[kt][0] = fmaf(cm.x, 3.0e4f, -3.0e4f);
      bias4[kt][1] = fmaf(cm.y, 3.0e4f, -3.0e4f);
      bias4[kt][2] = fmaf(cm.z, 3.0e4f, -3.0e4f);
      bias4[kt][3] = fmaf(cm.w, 3.0e4f, -3.0e4f);
    }
    __syncthreads();

    // S^T: s[kt][qt], rows = keys (kt*16+quad*4+reg), col = q (ln); C-init = mask bias
    f32x4 s[4][4];
#pragma unroll
    for (int kt = 0; kt < 4; kt++)
#pragma unroll
      for (int qt = 0; qt < 4; qt++) s[kt][qt] = bias4[kt];
#pragma unroll
    for (int kc = 0; kc < 2; kc++) {
#pragma unroll
      for (int kt = 0; kt < 4; kt++) {
        int r = kt * 16 + ln;
        f16x8 ka = *(const f16x8*)(Ks + ((size_t)r * 8 + ((kc * 4 + quad) ^ (r & 7))) * 8);
#pragma unroll
        for (int qt = 0; qt < 4; qt++)
          s[kt][qt] = __builtin_amdgcn_mfma_f32_16x16x32_f16(ka, qf[qt][kc], s[kt][qt], 0, 0, 0);
      }
    }

    // fixed-max softmax numerator: p = exp2(s), pack fp16, row-sum via dot2
#pragma unroll
    for (int qt = 0; qt < 4; qt++) {
      int qrow = qt * 16 + ln;
      ushort* pb = Ps + wave * (64 * 72) + qrow * 72;
      float rs = 0.f;
#pragma unroll
      for (int kt = 0; kt < 4; kt++) {
        float p0 = EXP2F(s[kt][qt][0]);
        float p1 = EXP2F(s[kt][qt][1]);
        float p2 = EXP2F(s[kt][qt][2]);
        float p3 = EXP2F(s[kt][qt][3]);
        uint2 pv;
        pv.x = pkrtz(p0, p1);
        pv.y = pkrtz(p2, p3);
        rs = dot2acc(pv.x, rs);
        rs = dot2acc(pv.y, rs);
        *(uint2*)(pb + (kt * 4 + quad) * 4) = pv;
      }
      rs += __shfl_xor(rs, 16, 64);
      rs += __shfl_xor(rs, 32, 64);
      lrun[qt] += rs;
    }
    __builtin_amdgcn_s_waitcnt(0);  // ds_writes visible to own wave before reads (lgkmcnt)

    // PV: o[dt][qt] += V^T(frag A) @ P^T(frag B)
#pragma unroll
    for (int kc = 0; kc < 2; kc++) {
      f16x8 pf[4];
#pragma unroll
      for (int qt = 0; qt < 4; qt++) {
        int qrow = qt * 16 + ln;
        pf[qt] = *(const f16x8*)(Ps + wave * (64 * 72) + qrow * 72 + (kc * 8 + quad * 2) * 4);
      }
#pragma unroll
      for (int dt = 0; dt < 4; dt++) {
        int r = dt * 16 + ln;
        f16x8 va = *(const f16x8*)(Vs + ((size_t)r * 8 + ((kc * 4 + quad) ^ (r & 7))) * 8);
#pragma unroll
        for (int qt = 0; qt < 4; qt++)
          o[dt][qt] = __builtin_amdgcn_mfma_f32_16x16x32_f16(va, pf[qt], o[dt][qt], 0, 0, 0);
      }
    }
  }

  // normalize + store O [b][n][h*64+d]
#pragma unroll
  for (int qt = 0; qt < 4; qt++) {
    float inv = (xm[qt] != 0.f && lrun[qt] > 0.f) ? (1.f / lrun[qt]) : 0.f;
    int n = q0 + qt * 16 + ln;
    ushort* ob = O + ((size_t)(b * 2048 + n) * 16 + h) * 64;
#pragma unroll
    for (int dt = 0; dt < 4; dt++) {
      uint2 pv;
      pv.x = pkrtz(o[dt][qt][0] * inv, o[dt][qt][1] * inv);
      pv.y = pkrtz(o[dt][qt][2] * inv, o[dt][qt][3] * inv);
      *(uint2*)(ob + dt * 16 + quad * 4) = pv;
    }
  }
}

// ---------------- host launcher ----------------
extern "C" void kernel_launch(void* const* d_in, const int* in_sizes, int n_in,
                              void* d_out, int out_size, void* d_ws, size_t ws_size,
                              hipStream_t stream) {
  const float* x   = (const float*)d_in[0];
  const float* ctx = (const float*)d_in[1];
  const float* xm  = (const float*)d_in[2];
  const float* cm  = (const float*)d_in[3];
  const float* Wq  = (const float*)d_in[4];
  const float* Wkv = (const float*)d_in[5];
  const float* Wo  = (const float*)d_in[6];
  const float* bo  = (const float*)d_in[7];

  char* ws = (char*)d_ws;
  const size_t MB = 1024 * 1024;
  ushort* xb   = (ushort*)(ws + 0);         // 16MB (x fp16; reused as O after QKV GEMM)
  ushort* cb   = (ushort*)(ws + 16 * MB);   // 16MB (context fp16)
  ushort* WqT  = (ushort*)(ws + 32 * MB);   // 2MB
  ushort* WkvT = (ushort*)(ws + 34 * MB);   // 4MB
  ushort* WoT  = (ushort*)(ws + 38 * MB);   // 2MB
  ushort* Qb   = (ushort*)(ws + 40 * MB);   // 16MB
  ushort* Kb   = (ushort*)(ws + 56 * MB);   // 16MB
  ushort* VTb  = (ushort*)(ws + 72 * MB);   // 16MB
  ushort* Ob   = xb;                        // alias: x fp16 dead after QKV GEMM

  cast_f16_kernel<<<16384, 256, 0, stream>>>((const float4*)x, (const float4*)ctx,
                                             (ushort4*)xb, (ushort4*)cb);
  transpose_cast_kernel<<<dim3(64, 16), 256, 0, stream>>>(Wq, Wkv, Wo, WqT, WkvT, WoT);
  qkv_gemm<<<dim3(24, 64), 256, 0, stream>>>(xb, cb, WqT, WkvT, Qb, Kb, VTb);
  attn_kernel<<<512, 256, 0, stream>>>(Qb, Kb, VTb, xm, cm, Ob);
  out_gemm<<<dim3(8, 64), 256, 0, stream>>>(Ob, WoT, (float*)d_out, bo);
}

// Round 3
// 320.721 us; speedup vs baseline: 1.1618x; 1.0604x over previous
//
#include <hip/hip_runtime.h>

#define DEVI __device__ __forceinline__

typedef __attribute__((ext_vector_type(4))) float f32x4;
typedef __attribute__((ext_vector_type(8))) _Float16 f16x8;
typedef __attribute__((ext_vector_type(2))) _Float16 f16x2;

#if __has_builtin(__builtin_amdgcn_exp2f)
#define EXP2F __builtin_amdgcn_exp2f
#else
#define EXP2F exp2f
#endif

DEVI ushort f2h(float f) {  // RNE scalar convert (v_cvt_f16_f32)
  _Float16 h = (_Float16)f;
  return __builtin_bit_cast(ushort, h);
}

DEVI unsigned pkrtz(float a, float b) {  // v_cvt_pkrtz_f16_f32
  return __builtin_bit_cast(unsigned, __builtin_amdgcn_cvt_pkrtz(a, b));
}

DEVI float dot2acc(unsigned pk, float acc) {
#if __has_builtin(__builtin_amdgcn_fdot2)
  f16x2 one2 = {(_Float16)1.0f, (_Float16)1.0f};
  return __builtin_amdgcn_fdot2(__builtin_bit_cast(f16x2, pk), one2, acc, false);
#else
  f16x2 v = __builtin_bit_cast(f16x2, pk);
  return acc + (float)v[0] + (float)v[1];
#endif
}

DEVI void gload_lds16(const void* g, void* l) {
  typedef const unsigned int GlobU __attribute__((address_space(1)));
  typedef unsigned int LdsU __attribute__((address_space(3)));
  __builtin_amdgcn_global_load_lds((GlobU*)g, (LdsU*)l, 16, 0, 0);
}

// ---------------- fused fp32 -> fp16 cast of x and context ----------------
__global__ __launch_bounds__(256) void cast_f16_kernel(
    const float4* __restrict__ x, const float4* __restrict__ ctx,
    ushort4* __restrict__ xo, ushort4* __restrict__ co) {
  int i = blockIdx.x * 256 + threadIdx.x;
  const float4* src;
  ushort4* dst;
  int j;
  if (i < 2097152) { src = x; dst = xo; j = i; }
  else             { src = ctx; dst = co; j = i - 2097152; }
  float4 v = src[j];
  ushort4 o;
  o.x = f2h(v.x); o.y = f2h(v.y); o.z = f2h(v.z); o.w = f2h(v.w);
  dst[j] = o;
}

// ---------------- fused transpose+cast of the 3 weights (all R=1024 rows) ----------------
__global__ __launch_bounds__(256) void transpose_cast_kernel(
    const float* __restrict__ Wq, const float* __restrict__ Wkv,
    const float* __restrict__ Wo, ushort* __restrict__ WqT,
    ushort* __restrict__ WkvT, ushort* __restrict__ WoT) {
  __shared__ ushort tile[64][65];
  int bx = blockIdx.x;
  const float* in; ushort* out; int C, cb;
  if (bx < 16)      { in = Wq;  out = WqT;  C = 1024; cb = bx * 64; }
  else if (bx < 48) { in = Wkv; out = WkvT; C = 2048; cb = (bx - 16) * 64; }
  else              { in = Wo;  out = WoT;  C = 1024; cb = (bx - 48) * 64; }
  const int R = 1024;
  int rb = blockIdx.y * 64;
  int t = threadIdx.x;
  int c4 = (t & 15) * 4, r0 = t >> 4;
#pragma unroll
  for (int i = 0; i < 4; i++) {
    int r = r0 + i * 16;
    float4 v = *(const float4*)(in + (size_t)(rb + r) * C + cb + c4);
    tile[r][c4 + 0] = f2h(v.x);
    tile[r][c4 + 1] = f2h(v.y);
    tile[r][c4 + 2] = f2h(v.z);
    tile[r][c4 + 3] = f2h(v.w);
  }
  __syncthreads();
#pragma unroll
  for (int i = 0; i < 4; i++) {
    int rr = r0 + i * 16;
    ushort4 o;
    o.x = tile[c4 + 0][rr]; o.y = tile[c4 + 1][rr];
    o.z = tile[c4 + 2][rr]; o.w = tile[c4 + 3][rr];
    *(ushort4*)(out + (size_t)(cb + rr) * R + rb + c4) = o;
  }
}

// ---------------- shared fp16 GEMM core: acc += A[M][K] @ Bt[N][K]^T tile ----------------
DEVI void gemm_core(const ushort* __restrict__ A, const ushort* __restrict__ Bt,
                    int K, int rowbase, int colbase, int tid,
                    ushort* As, ushort* Bs, f32x4 acc[4][4]) {
  const int lane = tid & 63, wave = tid >> 6;
  const int quad = lane >> 4, ln = lane & 15;
  const int wrow = (wave >> 1) * 64, wcol = (wave & 1) * 64;
  for (int k0 = 0; k0 < K; k0 += 32) {
    __syncthreads();
#pragma unroll
    for (int i = 0; i < 2; i++) {
      int f = i * 256 + tid;
      int r = f >> 2;
      int c = (f & 3) ^ (r & 3);
      gload_lds16(A + (size_t)(rowbase + r) * K + (k0 + c * 8),
                  (char*)As + (size_t)(i * 256 + wave * 64) * 16);
      gload_lds16(Bt + (size_t)(colbase + r) * K + (k0 + c * 8),
                  (char*)Bs + (size_t)(i * 256 + wave * 64) * 16);
    }
    __syncthreads();
    f16x8 a[4], b[4];
#pragma unroll
    for (int mt = 0; mt < 4; mt++) {
      int r = wrow + mt * 16 + ln;
      a[mt] = *(const f16x8*)(As + ((size_t)r * 4 + (quad ^ (r & 3))) * 8);
    }
#pragma unroll
    for (int nt = 0; nt < 4; nt++) {
      int r = wcol + nt * 16 + ln;
      b[nt] = *(const f16x8*)(Bs + ((size_t)r * 4 + (quad ^ (r & 3))) * 8);
    }
#pragma unroll
    for (int mt = 0; mt < 4; mt++)
#pragma unroll
      for (int nt = 0; nt < 4; nt++)
        acc[mt][nt] = __builtin_amdgcn_mfma_f32_16x16x32_f16(a[mt], b[nt], acc[mt][nt], 0, 0, 0);
  }
}

// ---------------- fused Q + KV projection GEMM ----------------
__global__ __launch_bounds__(256, 2) void qkv_gemm(
    const ushort* __restrict__ xb, const ushort* __restrict__ cb,
    const ushort* __restrict__ WqT, const ushort* __restrict__ WkvT,
    ushort* __restrict__ Qo, ushort* __restrict__ Ko, ushort* __restrict__ Vo) {
  __shared__ ushort As[128 * 32];
  __shared__ ushort Bs[128 * 32];
  const int tid = threadIdx.x;
  const int lane = tid & 63, wave = tid >> 6;
  const int quad = lane >> 4, ln = lane & 15;
  const int bx = blockIdx.x;
  const bool isQ = bx < 8;
  const int colbase = (isQ ? bx : bx - 8) * 128;
  const int rowbase = blockIdx.y * 128;
  const int wrow = (wave >> 1) * 64, wcol = (wave & 1) * 64;
  f32x4 acc[4][4] = {};
  gemm_core(isQ ? xb : cb, isQ ? WqT : WkvT, 1024, rowbase, colbase, tid, As, Bs, acc);

  if (isQ) {
    const float qscale = 0.18033688011112042f;  // 1/8 * log2(e)
#pragma unroll
    for (int nt = 0; nt < 4; nt++) {
      int col = colbase + wcol + nt * 16 + ln;
      int h = col >> 6, d = col & 63;
#pragma unroll
      for (int mt = 0; mt < 4; mt++) {
        int row = rowbase + wrow + mt * 16 + quad * 4;
#pragma unroll
        for (int r = 0; r < 4; r++) {
          int rr = row + r;
          int bb = rr >> 11, n = rr & 2047;
          Qo[(((size_t)bb * 16 + h) * 2048 + n) * 64 + d] = f2h(acc[mt][nt][r] * qscale);
        }
      }
    }
  } else {
    bool isK = (colbase < 1024);
#pragma unroll
    for (int nt = 0; nt < 4; nt++) {
      int col = colbase + wcol + nt * 16 + ln;
#pragma unroll
      for (int mt = 0; mt < 4; mt++) {
        int row = rowbase + wrow + mt * 16 + quad * 4;
        int bb = row >> 11, m = row & 2047;
        if (isK) {
          int h = col >> 6, d = col & 63;
#pragma unroll
          for (int r = 0; r < 4; r++)
            Ko[(((size_t)bb * 16 + h) * 2048 + (m + r)) * 64 + d] = f2h(acc[mt][nt][r]);
        } else {
          int c2 = col - 1024;
          int h = c2 >> 6, d = c2 & 63;
          uint2 pv;
          pv.x = pkrtz(acc[mt][nt][0], acc[mt][nt][1]);
          pv.y = pkrtz(acc[mt][nt][2], acc[mt][nt][3]);
          *(uint2*)(Vo + (((size_t)bb * 16 + h) * 64 + d) * 2048 + m) = pv;
        }
      }
    }
  }
}

// ---------------- out projection: fp32 [M][N] = A @ WoT^T + bias ----------------
__global__ __launch_bounds__(256, 2) void out_gemm(
    const ushort* __restrict__ A, const ushort* __restrict__ Bt,
    float* __restrict__ C, const float* __restrict__ bias) {
  __shared__ ushort As[128 * 32];
  __shared__ ushort Bs[128 * 32];
  const int tid = threadIdx.x;
  const int lane = tid & 63, wave = tid >> 6;
  const int quad = lane >> 4, ln = lane & 15;
  const int colbase = blockIdx.x * 128, rowbase = blockIdx.y * 128;
  const int wrow = (wave >> 1) * 64, wcol = (wave & 1) * 64;
  f32x4 acc[4][4] = {};
  gemm_core(A, Bt, 1024, rowbase, colbase, tid, As, Bs, acc);
#pragma unroll
  for (int nt = 0; nt < 4; nt++) {
    int col = colbase + wcol + nt * 16 + ln;
    float bv = bias[col];
#pragma unroll
    for (int mt = 0; mt < 4; mt++) {
      int row = rowbase + wrow + mt * 16 + quad * 4;
#pragma unroll
      for (int r = 0; r < 4; r++)
        C[(size_t)(row + r) * 1024 + col] = acc[mt][nt][r] + bv;
    }
  }
}

// ---------------- flash attention: dbuf async prefetch, fixed-max softmax ----------------
// S^T = K @ Q^T; Q pre-scaled by 0.125*log2e; p = exp2(s + maskbias).
// Double-buffered K/V via global_load_lds kept in flight across raw s_barriers
// (s_waitcnt vmcnt(4): wait own tile-kb loads, tile-kb+1 stays pending).
// In-loop VMEM = tile loads ONLY (cmask bias pre-staged in LDS) so vmcnt math is exact.
__global__ __launch_bounds__(256, 2) void attn_kernel(
    const ushort* __restrict__ Q, const ushort* __restrict__ K,
    const ushort* __restrict__ VT, const float* __restrict__ xmask,
    const float* __restrict__ cmask, ushort* __restrict__ O) {
  __shared__ ushort Ks[2][64 * 64];
  __shared__ ushort Vs[2][64 * 64];
  __shared__ ushort Ps[4 * 64 * 40];  // per-wave [64 q][32 keys + 8 pad] fp16 (kc-half)
  __shared__ float CMB[2048];         // (cmask-1)*3e4 bias, whole context row
  const int tid = threadIdx.x, lane = tid & 63, wave = tid >> 6;
  const int quad = lane >> 4, ln = lane & 15;
  const int bid = blockIdx.x;
  const int qb = bid & 7, h = (bid >> 3) & 15, b = bid >> 7;
  const size_t bh = (size_t)b * 16 + h;
  const ushort* Qbh = Q + bh * (2048 * 64);
  const ushort* Kbh = K + bh * (2048 * 64);
  const ushort* Vbh = VT + bh * (64 * 2048);
  const int q0 = qb * 256 + wave * 64;

  // one-time: stage mask bias into LDS (0 valid / -3e4 masked)
  {
    float4 c0 = *(const float4*)(cmask + b * 2048 + tid * 8);
    float4 c1 = *(const float4*)(cmask + b * 2048 + tid * 8 + 4);
    float4 b0, b1;
    b0.x = fmaf(c0.x, 3.0e4f, -3.0e4f); b0.y = fmaf(c0.y, 3.0e4f, -3.0e4f);
    b0.z = fmaf(c0.z, 3.0e4f, -3.0e4f); b0.w = fmaf(c0.w, 3.0e4f, -3.0e4f);
    b1.x = fmaf(c1.x, 3.0e4f, -3.0e4f); b1.y = fmaf(c1.y, 3.0e4f, -3.0e4f);
    b1.z = fmaf(c1.z, 3.0e4f, -3.0e4f); b1.w = fmaf(c1.w, 3.0e4f, -3.0e4f);
    *(float4*)(CMB + tid * 8) = b0;
    *(float4*)(CMB + tid * 8 + 4) = b1;
  }

  // Q fragments (B-operand: n=q=ln, k=d=quad*8+j (+32*kc)), held in registers
  f16x8 qf[4][2];
#pragma unroll
  for (int qt = 0; qt < 4; qt++)
#pragma unroll
    for (int kc = 0; kc < 2; kc++)
      qf[qt][kc] = *(const f16x8*)(Qbh + (size_t)(q0 + qt * 16 + ln) * 64 + kc * 32 + quad * 8);

  float xm[4];
#pragma unroll
  for (int qt = 0; qt < 4; qt++) xm[qt] = xmask[b * 2048 + q0 + qt * 16 + ln];

  __syncthreads();  // CMB staged (drains everything; prefetch starts after)

  // prologue: prefetch tiles 0 and 1 (4 vm-ops per thread per tile)
#pragma unroll
  for (int t = 0; t < 2; t++) {
#pragma unroll
    for (int i = 0; i < 2; i++) {
      int f = i * 256 + tid;
      int r = f >> 3;
      int c = (f & 7) ^ (r & 7);
      gload_lds16(Kbh + (size_t)(t * 64 + r) * 64 + c * 8,
                  (char*)Ks[t] + (size_t)(i * 256 + wave * 64) * 16);
      gload_lds16(Vbh + (size_t)r * 2048 + (t * 64 + c * 8),
                  (char*)Vs[t] + (size_t)(i * 256 + wave * 64) * 16);
    }
  }

  f32x4 o[4][4] = {};  // o[dt][qt]: rows d = dt*16+quad*4+r, col q = ln
  float lrun[4] = {0.f, 0.f, 0.f, 0.f};

  for (int kb = 0; kb < 32; kb++) {
    const int cur = kb & 1;
    const int m0 = kb * 64;
    const ushort* KsC = Ks[cur];
    const ushort* VsC = Vs[cur];

    // tile kb ready (own 4 loads done; kb+1's stay in flight), then sync
    if (kb < 31) asm volatile("s_waitcnt vmcnt(4)" ::: "memory");
    else         asm volatile("s_waitcnt vmcnt(0)" ::: "memory");
    asm volatile("s_barrier" ::: "memory");

    // mask bias from LDS (broadcast reads)
    f32x4 bias4[4];
#pragma unroll
    for (int kt = 0; kt < 4; kt++)
      bias4[kt] = *(const f32x4*)(CMB + m0 + kt * 16 + quad * 4);

    // S^T: s[kt][qt], rows = keys (kt*16+quad*4+reg), col = q (ln); C-init = mask bias
    f32x4 s[4][4];
#pragma unroll
    for (int kt = 0; kt < 4; kt++)
#pragma unroll
      for (int qt = 0; qt < 4; qt++) s[kt][qt] = bias4[kt];
#pragma unroll
    for (int kc = 0; kc < 2; kc++) {
#pragma unroll
      for (int kt = 0; kt < 4; kt++) {
        int r = kt * 16 + ln;
        f16x8 ka = *(const f16x8*)(KsC + ((size_t)r * 8 + ((kc * 4 + quad) ^ (r & 7))) * 8);
#pragma unroll
        for (int qt = 0; qt < 4; qt++)
          s[kt][qt] = __builtin_amdgcn_mfma_f32_16x16x32_f16(ka, qf[qt][kc], s[kt][qt], 0, 0, 0);
      }
    }

    // split-P: per 32-key half: exp2 -> pack -> Ps -> PV MFMA (halves pipeline VALU vs MFMA)
    float rs[4] = {0.f, 0.f, 0.f, 0.f};
#pragma unroll
    for (int kc = 0; kc < 2; kc++) {
#pragma unroll
      for (int qt = 0; qt < 4; qt++) {
        int qrow = qt * 16 + ln;
        ushort* pb = Ps + wave * (64 * 40) + qrow * 40;
#pragma unroll
        for (int t = 0; t < 2; t++) {
          int kt = kc * 2 + t;
          float p0 = EXP2F(s[kt][qt][0]);
          float p1 = EXP2F(s[kt][qt][1]);
          float p2 = EXP2F(s[kt][qt][2]);
          float p3 = EXP2F(s[kt][qt][3]);
          uint2 pv;
          pv.x = pkrtz(p0, p1);
          pv.y = pkrtz(p2, p3);
          rs[qt] = dot2acc(pv.x, rs[qt]);
          rs[qt] = dot2acc(pv.y, rs[qt]);
          *(uint2*)(pb + (t * 4 + quad) * 4) = pv;
        }
      }
      // PV half: o[dt][qt] += V^T(frag A, keys kc*32..) @ P^T(frag B)
      f16x8 pf[4];
#pragma unroll
      for (int qt = 0; qt < 4; qt++) {
        int qrow = qt * 16 + ln;
        pf[qt] = *(const f16x8*)(Ps + wave * (64 * 40) + qrow * 40 + quad * 8);
      }
#pragma unroll
      for (int dt = 0; dt < 4; dt++) {
        int r = dt * 16 + ln;
        f16x8 va = *(const f16x8*)(VsC + ((size_t)r * 8 + ((kc * 4 + quad) ^ (r & 7))) * 8);
#pragma unroll
        for (int qt = 0; qt < 4; qt++)
          o[dt][qt] = __builtin_amdgcn_mfma_f32_16x16x32_f16(va, pf[qt], o[dt][qt], 0, 0, 0);
      }
    }
#pragma unroll
    for (int qt = 0; qt < 4; qt++) {
      float r2 = rs[qt];
      r2 += __shfl_xor(r2, 16, 64);
      r2 += __shfl_xor(r2, 32, 64);
      lrun[qt] += r2;
    }

    // all waves done reading buf[cur]; refill it with tile kb+2
    asm volatile("s_barrier" ::: "memory");
    if (kb < 30) {
      const int m2 = m0 + 128;
#pragma unroll
      for (int i = 0; i < 2; i++) {
        int f = i * 256 + tid;
        int r = f >> 3;
        int c = (f & 7) ^ (r & 7);
        gload_lds16(Kbh + (size_t)(m2 + r) * 64 + c * 8,
                    (char*)Ks[cur] + (size_t)(i * 256 + wave * 64) * 16);
        gload_lds16(Vbh + (size_t)r * 2048 + (m2 + c * 8),
                    (char*)Vs[cur] + (size_t)(i * 256 + wave * 64) * 16);
      }
    }
  }

  // normalize + store O [b][n][h*64+d]
#pragma unroll
  for (int qt = 0; qt < 4; qt++) {
    float inv = (xm[qt] != 0.f && lrun[qt] > 0.f) ? (1.f / lrun[qt]) : 0.f;
    int n = q0 + qt * 16 + ln;
    ushort* ob = O + ((size_t)(b * 2048 + n) * 16 + h) * 64;
#pragma unroll
    for (int dt = 0; dt < 4; dt++) {
      uint2 pv;
      pv.x = pkrtz(o[dt][qt][0] * inv, o[dt][qt][1] * inv);
      pv.y = pkrtz(o[dt][qt][2] * inv, o[dt][qt][3] * inv);
      *(uint2*)(ob + dt * 16 + quad * 4) = pv;
    }
  }
}

// ---------------- host launcher ----------------
extern "C" void kernel_launch(void* const* d_in, const int* in_sizes, int n_in,
                              void* d_out, int out_size, void* d_ws, size_t ws_size,
                              hipStream_t stream) {
  const float* x   = (const float*)d_in[0];
  const float* ctx = (const float*)d_in[1];
  const float* xm  = (const float*)d_in[2];
  const float* cm  = (const float*)d_in[3];
  const float* Wq  = (const float*)d_in[4];
  const float* Wkv = (const float*)d_in[5];
  const float* Wo  = (const float*)d_in[6];
  const float* bo  = (const float*)d_in[7];

  char* ws = (char*)d_ws;
  const size_t MB = 1024 * 1024;
  ushort* xb   = (ushort*)(ws + 0);         // 16MB (x fp16; reused as O after QKV GEMM)
  ushort* cb   = (ushort*)(ws + 16 * MB);   // 16MB (context fp16)
  ushort* WqT  = (ushort*)(ws + 32 * MB);   // 2MB
  ushort* WkvT = (ushort*)(ws + 34 * MB);   // 4MB
  ushort* WoT  = (ushort*)(ws + 38 * MB);   // 2MB
  ushort* Qb   = (ushort*)(ws + 40 * MB);   // 16MB
  ushort* Kb   = (ushort*)(ws + 56 * MB);   // 16MB
  ushort* VTb  = (ushort*)(ws + 72 * MB);   // 16MB
  ushort* Ob   = xb;                        // alias: x fp16 dead after QKV GEMM

  cast_f16_kernel<<<16384, 256, 0, stream>>>((const float4*)x, (const float4*)ctx,
                                             (ushort4*)xb, (ushort4*)cb);
  transpose_cast_kernel<<<dim3(64, 16), 256, 0, stream>>>(Wq, Wkv, Wo, WqT, WkvT, WoT);
  qkv_gemm<<<dim3(24, 64), 256, 0, stream>>>(xb, cb, WqT, WkvT, Qb, Kb, VTb);
  attn_kernel<<<512, 256, 0, stream>>>(Qb, Kb, VTb, xm, cm, Ob);
  out_gemm<<<dim3(8, 64), 256, 0, stream>>>(Ob, WoT, (float*)d_out, bo);
}

// Round 4
// 313.441 us; speedup vs baseline: 1.1887x; 1.0232x over previous
//
#include <hip/hip_runtime.h>

#define DEVI __device__ __forceinline__

typedef __attribute__((ext_vector_type(4))) float f32x4;
typedef __attribute__((ext_vector_type(8))) _Float16 f16x8;
typedef __attribute__((ext_vector_type(2))) _Float16 f16x2;

#if __has_builtin(__builtin_amdgcn_exp2f)
#define EXP2F __builtin_amdgcn_exp2f
#else
#define EXP2F exp2f
#endif

DEVI ushort f2h(float f) {  // RNE scalar convert (v_cvt_f16_f32)
  _Float16 h = (_Float16)f;
  return __builtin_bit_cast(ushort, h);
}

DEVI unsigned pkrtz(float a, float b) {  // v_cvt_pkrtz_f16_f32
  return __builtin_bit_cast(unsigned, __builtin_amdgcn_cvt_pkrtz(a, b));
}

DEVI float dot2acc(unsigned pk, float acc) {
#if __has_builtin(__builtin_amdgcn_fdot2)
  f16x2 one2 = {(_Float16)1.0f, (_Float16)1.0f};
  return __builtin_amdgcn_fdot2(__builtin_bit_cast(f16x2, pk), one2, acc, false);
#else
  f16x2 v = __builtin_bit_cast(f16x2, pk);
  return acc + (float)v[0] + (float)v[1];
#endif
}

DEVI void gload_lds16(const void* g, void* l) {
  typedef const unsigned int GlobU __attribute__((address_space(1)));
  typedef unsigned int LdsU __attribute__((address_space(3)));
  __builtin_amdgcn_global_load_lds((GlobU*)g, (LdsU*)l, 16, 0, 0);
}

// ---------------- fused fp32 -> fp16 cast of x and context ----------------
__global__ __launch_bounds__(256) void cast_f16_kernel(
    const float4* __restrict__ x, const float4* __restrict__ ctx,
    ushort4* __restrict__ xo, ushort4* __restrict__ co) {
  int i = blockIdx.x * 256 + threadIdx.x;
  const float4* src;
  ushort4* dst;
  int j;
  if (i < 2097152) { src = x; dst = xo; j = i; }
  else             { src = ctx; dst = co; j = i - 2097152; }
  float4 v = src[j];
  ushort4 o;
  o.x = f2h(v.x); o.y = f2h(v.y); o.z = f2h(v.z); o.w = f2h(v.w);
  dst[j] = o;
}

// ---------------- fused transpose+cast of the 3 weights (all R=1024 rows) ----------------
__global__ __launch_bounds__(256) void transpose_cast_kernel(
    const float* __restrict__ Wq, const float* __restrict__ Wkv,
    const float* __restrict__ Wo, ushort* __restrict__ WqT,
    ushort* __restrict__ WkvT, ushort* __restrict__ WoT) {
  __shared__ ushort tile[64][65];
  int bx = blockIdx.x;
  const float* in; ushort* out; int C, cb;
  if (bx < 16)      { in = Wq;  out = WqT;  C = 1024; cb = bx * 64; }
  else if (bx < 48) { in = Wkv; out = WkvT; C = 2048; cb = (bx - 16) * 64; }
  else              { in = Wo;  out = WoT;  C = 1024; cb = (bx - 48) * 64; }
  const int R = 1024;
  int rb = blockIdx.y * 64;
  int t = threadIdx.x;
  int c4 = (t & 15) * 4, r0 = t >> 4;
#pragma unroll
  for (int i = 0; i < 4; i++) {
    int r = r0 + i * 16;
    float4 v = *(const float4*)(in + (size_t)(rb + r) * C + cb + c4);
    tile[r][c4 + 0] = f2h(v.x);
    tile[r][c4 + 1] = f2h(v.y);
    tile[r][c4 + 2] = f2h(v.z);
    tile[r][c4 + 3] = f2h(v.w);
  }
  __syncthreads();
#pragma unroll
  for (int i = 0; i < 4; i++) {
    int rr = r0 + i * 16;
    ushort4 o;
    o.x = tile[c4 + 0][rr]; o.y = tile[c4 + 1][rr];
    o.z = tile[c4 + 2][rr]; o.w = tile[c4 + 3][rr];
    *(ushort4*)(out + (size_t)(cb + rr) * R + rb + c4) = o;
  }
}

// ---------------- shared fp16 GEMM core: acc += A[M][K] @ Bt[N][K]^T tile ----------------
DEVI void gemm_core(const ushort* __restrict__ A, const ushort* __restrict__ Bt,
                    int K, int rowbase, int colbase, int tid,
                    ushort* As, ushort* Bs, f32x4 acc[4][4]) {
  const int lane = tid & 63, wave = tid >> 6;
  const int quad = lane >> 4, ln = lane & 15;
  const int wrow = (wave >> 1) * 64, wcol = (wave & 1) * 64;
  for (int k0 = 0; k0 < K; k0 += 32) {
    __syncthreads();
#pragma unroll
    for (int i = 0; i < 2; i++) {
      int f = i * 256 + tid;
      int r = f >> 2;
      int c = (f & 3) ^ (r & 3);
      gload_lds16(A + (size_t)(rowbase + r) * K + (k0 + c * 8),
                  (char*)As + (size_t)(i * 256 + wave * 64) * 16);
      gload_lds16(Bt + (size_t)(colbase + r) * K + (k0 + c * 8),
                  (char*)Bs + (size_t)(i * 256 + wave * 64) * 16);
    }
    __syncthreads();
    f16x8 a[4], b[4];
#pragma unroll
    for (int mt = 0; mt < 4; mt++) {
      int r = wrow + mt * 16 + ln;
      a[mt] = *(const f16x8*)(As + ((size_t)r * 4 + (quad ^ (r & 3))) * 8);
    }
#pragma unroll
    for (int nt = 0; nt < 4; nt++) {
      int r = wcol + nt * 16 + ln;
      b[nt] = *(const f16x8*)(Bs + ((size_t)r * 4 + (quad ^ (r & 3))) * 8);
    }
#pragma unroll
    for (int mt = 0; mt < 4; mt++)
#pragma unroll
      for (int nt = 0; nt < 4; nt++)
        acc[mt][nt] = __builtin_amdgcn_mfma_f32_16x16x32_f16(a[mt], b[nt], acc[mt][nt], 0, 0, 0);
  }
}

// ---------------- fused Q + KV projection GEMM ----------------
// grid (64 rows, 24 coltiles): xcd = linear%8 = rowtile%8 -> A row-block stays in one XCD's L2
__global__ __launch_bounds__(256, 2) void qkv_gemm(
    const ushort* __restrict__ xb, const ushort* __restrict__ cb,
    const ushort* __restrict__ WqT, const ushort* __restrict__ WkvT,
    ushort* __restrict__ Qo, ushort* __restrict__ Ko, ushort* __restrict__ Vo) {
  __shared__ ushort As[128 * 32];
  __shared__ ushort Bs[128 * 32];
  const int tid = threadIdx.x;
  const int lane = tid & 63, wave = tid >> 6;
  const int quad = lane >> 4, ln = lane & 15;
  const int cy = blockIdx.y;
  const bool isQ = cy < 8;
  const int colbase = (isQ ? cy : cy - 8) * 128;
  const int rowbase = blockIdx.x * 128;
  const int wrow = (wave >> 1) * 64, wcol = (wave & 1) * 64;
  f32x4 acc[4][4] = {};
  gemm_core(isQ ? xb : cb, isQ ? WqT : WkvT, 1024, rowbase, colbase, tid, As, Bs, acc);

  if (isQ) {
    const float qscale = 0.18033688011112042f;  // 1/8 * log2(e)
#pragma unroll
    for (int nt = 0; nt < 4; nt++) {
      int col = colbase + wcol + nt * 16 + ln;
      int h = col >> 6, d = col & 63;
#pragma unroll
      for (int mt = 0; mt < 4; mt++) {
        int row = rowbase + wrow + mt * 16 + quad * 4;
#pragma unroll
        for (int r = 0; r < 4; r++) {
          int rr = row + r;
          int bb = rr >> 11, n = rr & 2047;
          Qo[(((size_t)bb * 16 + h) * 2048 + n) * 64 + d] = f2h(acc[mt][nt][r] * qscale);
        }
      }
    }
  } else {
    bool isK = (colbase < 1024);
#pragma unroll
    for (int nt = 0; nt < 4; nt++) {
      int col = colbase + wcol + nt * 16 + ln;
#pragma unroll
      for (int mt = 0; mt < 4; mt++) {
        int row = rowbase + wrow + mt * 16 + quad * 4;
        int bb = row >> 11, m = row & 2047;
        if (isK) {
          int h = col >> 6, d = col & 63;
#pragma unroll
          for (int r = 0; r < 4; r++)
            Ko[(((size_t)bb * 16 + h) * 2048 + (m + r)) * 64 + d] = f2h(acc[mt][nt][r]);
        } else {
          int c2 = col - 1024;
          int h = c2 >> 6, d = c2 & 63;
          uint2 pv;
          pv.x = pkrtz(acc[mt][nt][0], acc[mt][nt][1]);
          pv.y = pkrtz(acc[mt][nt][2], acc[mt][nt][3]);
          *(uint2*)(Vo + (((size_t)bb * 16 + h) * 64 + d) * 2048 + m) = pv;
        }
      }
    }
  }
}

// ---------------- out projection: fp32 [M][N] = A @ WoT^T + bias ----------------
// grid (64 rows, 8 coltiles): same XCD-affinity trick
__global__ __launch_bounds__(256, 2) void out_gemm(
    const ushort* __restrict__ A, const ushort* __restrict__ Bt,
    float* __restrict__ C, const float* __restrict__ bias) {
  __shared__ ushort As[128 * 32];
  __shared__ ushort Bs[128 * 32];
  const int tid = threadIdx.x;
  const int lane = tid & 63, wave = tid >> 6;
  const int quad = lane >> 4, ln = lane & 15;
  const int colbase = blockIdx.y * 128, rowbase = blockIdx.x * 128;
  const int wrow = (wave >> 1) * 64, wcol = (wave & 1) * 64;
  f32x4 acc[4][4] = {};
  gemm_core(A, Bt, 1024, rowbase, colbase, tid, As, Bs, acc);
#pragma unroll
  for (int nt = 0; nt < 4; nt++) {
    int col = colbase + wcol + nt * 16 + ln;
    float bv = bias[col];
#pragma unroll
    for (int mt = 0; mt < 4; mt++) {
      int row = rowbase + wrow + mt * 16 + quad * 4;
#pragma unroll
      for (int r = 0; r < 4; r++)
        C[(size_t)(row + r) * 1024 + col] = acc[mt][nt][r] + bv;
    }
  }
}

// ---------------- flash attention: 8 waves/block, 32 q/wave, dbuf prefetch ----------------
// S^T = K @ Q^T; Q pre-scaled by 0.125*log2e; p = exp2(s + maskbias), fixed max.
// 512-thread blocks share K/V staging (same LDS, 2x waves/SIMD vs 4-wave version).
// In-loop VMEM = 2 tile loads/thread only, so vmcnt(2) = own tile done, next in flight.
// Block swizzle: bid&63 = (b,h) -> all 8 q-blocks of a (b,h) on one XCD (K/V L2 reuse).
__global__ __launch_bounds__(512, 4) void attn_kernel(
    const ushort* __restrict__ Q, const ushort* __restrict__ K,
    const ushort* __restrict__ VT, const float* __restrict__ xmask,
    const float* __restrict__ cmask, ushort* __restrict__ O) {
  __shared__ ushort Ks[2][64 * 64];
  __shared__ ushort Vs[2][64 * 64];
  __shared__ ushort Ps[8 * 32 * 40];  // per-wave [32 q][32 keys + 8 pad] fp16
  __shared__ float CMB[2048];         // (cmask-1)*3e4 bias, whole context row
  const int tid = threadIdx.x, lane = tid & 63, wave = tid >> 6;  // wave 0..7
  const int quad = lane >> 4, ln = lane & 15;
  const int bid = blockIdx.x;
  const int qb = bid >> 6, bh6 = bid & 63, h = bh6 & 15, b = bh6 >> 4;
  const size_t bh = (size_t)b * 16 + h;
  const ushort* Qbh = Q + bh * (2048 * 64);
  const ushort* Kbh = K + bh * (2048 * 64);
  const ushort* Vbh = VT + bh * (64 * 2048);
  const int q0 = qb * 256 + wave * 32;

  // one-time: stage mask bias into LDS (0 valid / -3e4 masked)
  {
    float4 c0 = *(const float4*)(cmask + b * 2048 + tid * 4);
    float4 b0;
    b0.x = fmaf(c0.x, 3.0e4f, -3.0e4f); b0.y = fmaf(c0.y, 3.0e4f, -3.0e4f);
    b0.z = fmaf(c0.z, 3.0e4f, -3.0e4f); b0.w = fmaf(c0.w, 3.0e4f, -3.0e4f);
    *(float4*)(CMB + tid * 4) = b0;
  }

  // Q fragments (B-operand: n=q=ln, k=d=quad*8+j (+32*kc)), held in registers
  f16x8 qf[2][2];
#pragma unroll
  for (int qt = 0; qt < 2; qt++)
#pragma unroll
    for (int kc = 0; kc < 2; kc++)
      qf[qt][kc] = *(const f16x8*)(Qbh + (size_t)(q0 + qt * 16 + ln) * 64 + kc * 32 + quad * 8);

  float xm[2];
#pragma unroll
  for (int qt = 0; qt < 2; qt++) xm[qt] = xmask[b * 2048 + q0 + qt * 16 + ln];

  __syncthreads();  // CMB staged (drains everything; prefetch starts after)

  // prologue: prefetch tiles 0 and 1 (1 K-load + 1 V-load per thread per tile)
  {
    int r = tid >> 3;
    int c = (tid & 7) ^ (r & 7);
#pragma unroll
    for (int t = 0; t < 2; t++) {
      gload_lds16(Kbh + (size_t)(t * 64 + r) * 64 + c * 8, (char*)Ks[t] + (size_t)tid * 16);
      gload_lds16(Vbh + (size_t)r * 2048 + (t * 64 + c * 8), (char*)Vs[t] + (size_t)tid * 16);
    }
  }

  f32x4 o[4][2] = {};  // o[dt][qt]: rows d = dt*16+quad*4+r, col q = ln
  float lpart[2] = {0.f, 0.f};  // per-lane partial row sums (reduced once at end)

  for (int kb = 0; kb < 32; kb++) {
    const int cur = kb & 1;
    const int m0 = kb * 64;
    const ushort* KsC = Ks[cur];
    const ushort* VsC = Vs[cur];

    // tile kb ready (own 2 loads done; kb+1's 2 stay in flight), then sync
    if (kb < 31) asm volatile("s_waitcnt vmcnt(2)" ::: "memory");
    else         asm volatile("s_waitcnt vmcnt(0)" ::: "memory");
    asm volatile("s_barrier" ::: "memory");

    // mask bias from LDS (broadcast reads)
    f32x4 bias4[4];
#pragma unroll
    for (int kt = 0; kt < 4; kt++)
      bias4[kt] = *(const f32x4*)(CMB + m0 + kt * 16 + quad * 4);

    // S^T: s[kt][qt], rows = keys (kt*16+quad*4+reg), col = q (ln); C-init = mask bias
    f32x4 s[4][2];
#pragma unroll
    for (int kt = 0; kt < 4; kt++)
#pragma unroll
      for (int qt = 0; qt < 2; qt++) s[kt][qt] = bias4[kt];
#pragma unroll
    for (int kc = 0; kc < 2; kc++) {
#pragma unroll
      for (int kt = 0; kt < 4; kt++) {
        int r = kt * 16 + ln;
        f16x8 ka = *(const f16x8*)(KsC + ((size_t)r * 8 + ((kc * 4 + quad) ^ (r & 7))) * 8);
#pragma unroll
        for (int qt = 0; qt < 2; qt++)
          s[kt][qt] = __builtin_amdgcn_mfma_f32_16x16x32_f16(ka, qf[qt][kc], s[kt][qt], 0, 0, 0);
      }
    }

    // split-P: per 32-key half: exp2 -> pack -> Ps -> PV MFMA
#pragma unroll
    for (int kc = 0; kc < 2; kc++) {
#pragma unroll
      for (int qt = 0; qt < 2; qt++) {
        int qrow = qt * 16 + ln;
        ushort* pb = Ps + wave * (32 * 40) + qrow * 40;
#pragma unroll
        for (int t = 0; t < 2; t++) {
          int kt = kc * 2 + t;
          float p0 = EXP2F(s[kt][qt][0]);
          float p1 = EXP2F(s[kt][qt][1]);
          float p2 = EXP2F(s[kt][qt][2]);
          float p3 = EXP2F(s[kt][qt][3]);
          uint2 pv;
          pv.x = pkrtz(p0, p1);
          pv.y = pkrtz(p2, p3);
          lpart[qt] = dot2acc(pv.x, lpart[qt]);
          lpart[qt] = dot2acc(pv.y, lpart[qt]);
          *(uint2*)(pb + (t * 4 + quad) * 4) = pv;
        }
      }
      // PV half: o[dt][qt] += V^T(frag A, keys kc*32..) @ P^T(frag B)
      f16x8 pf[2];
#pragma unroll
      for (int qt = 0; qt < 2; qt++) {
        int qrow = qt * 16 + ln;
        pf[qt] = *(const f16x8*)(Ps + wave * (32 * 40) + qrow * 40 + quad * 8);
      }
#pragma unroll
      for (int dt = 0; dt < 4; dt++) {
        int r = dt * 16 + ln;
        f16x8 va = *(const f16x8*)(VsC + ((size_t)r * 8 + ((kc * 4 + quad) ^ (r & 7))) * 8);
#pragma unroll
        for (int qt = 0; qt < 2; qt++)
          o[dt][qt] = __builtin_amdgcn_mfma_f32_16x16x32_f16(va, pf[qt], o[dt][qt], 0, 0, 0);
      }
    }

    // all waves done reading buf[cur]; refill it with tile kb+2
    asm volatile("s_barrier" ::: "memory");
    if (kb < 30) {
      const int m2 = m0 + 128;
      int r = tid >> 3;
      int c = (tid & 7) ^ (r & 7);
      gload_lds16(Kbh + (size_t)(m2 + r) * 64 + c * 8, (char*)Ks[cur] + (size_t)tid * 16);
      gload_lds16(Vbh + (size_t)r * 2048 + (m2 + c * 8), (char*)Vs[cur] + (size_t)tid * 16);
    }
  }

  // normalize + store O [b][n][h*64+d]
#pragma unroll
  for (int qt = 0; qt < 2; qt++) {
    float l = lpart[qt];
    l += __shfl_xor(l, 16, 64);
    l += __shfl_xor(l, 32, 64);
    float inv = (xm[qt] != 0.f && l > 0.f) ? (1.f / l) : 0.f;
    int n = q0 + qt * 16 + ln;
    ushort* ob = O + ((size_t)(b * 2048 + n) * 16 + h) * 64;
#pragma unroll
    for (int dt = 0; dt < 4; dt++) {
      uint2 pv;
      pv.x = pkrtz(o[dt][qt][0] * inv, o[dt][qt][1] * inv);
      pv.y = pkrtz(o[dt][qt][2] * inv, o[dt][qt][3] * inv);
      *(uint2*)(ob + dt * 16 + quad * 4) = pv;
    }
  }
}

// ---------------- host launcher ----------------
extern "C" void kernel_launch(void* const* d_in, const int* in_sizes, int n_in,
                              void* d_out, int out_size, void* d_ws, size_t ws_size,
                              hipStream_t stream) {
  const float* x   = (const float*)d_in[0];
  const float* ctx = (const float*)d_in[1];
  const float* xm  = (const float*)d_in[2];
  const float* cm  = (const float*)d_in[3];
  const float* Wq  = (const float*)d_in[4];
  const float* Wkv = (const float*)d_in[5];
  const float* Wo  = (const float*)d_in[6];
  const float* bo  = (const float*)d_in[7];

  char* ws = (char*)d_ws;
  const size_t MB = 1024 * 1024;
  ushort* xb   = (ushort*)(ws + 0);         // 16MB (x fp16; reused as O after QKV GEMM)
  ushort* cb   = (ushort*)(ws + 16 * MB);   // 16MB (context fp16)
  ushort* WqT  = (ushort*)(ws + 32 * MB);   // 2MB
  ushort* WkvT = (ushort*)(ws + 34 * MB);   // 4MB
  ushort* WoT  = (ushort*)(ws + 38 * MB);   // 2MB
  ushort* Qb   = (ushort*)(ws + 40 * MB);   // 16MB
  ushort* Kb   = (ushort*)(ws + 56 * MB);   // 16MB
  ushort* VTb  = (ushort*)(ws + 72 * MB);   // 16MB
  ushort* Ob   = xb;                        // alias: x fp16 dead after QKV GEMM

  cast_f16_kernel<<<16384, 256, 0, stream>>>((const float4*)x, (const float4*)ctx,
                                             (ushort4*)xb, (ushort4*)cb);
  transpose_cast_kernel<<<dim3(64, 16), 256, 0, stream>>>(Wq, Wkv, Wo, WqT, WkvT, WoT);
  qkv_gemm<<<dim3(64, 24), 256, 0, stream>>>(xb, cb, WqT, WkvT, Qb, Kb, VTb);
  attn_kernel<<<512, 512, 0, stream>>>(Qb, Kb, VTb, xm, cm, Ob);
  out_gemm<<<dim3(64, 8), 256, 0, stream>>>(Ob, WoT, (float*)d_out, bo);
}

// Round 5
// 299.069 us; speedup vs baseline: 1.2459x; 1.0481x over previous
//
#include <hip/hip_runtime.h>

#define DEVI __device__ __forceinline__

typedef __attribute__((ext_vector_type(4))) float f32x4;
typedef __attribute__((ext_vector_type(8))) _Float16 f16x8;
typedef __attribute__((ext_vector_type(2))) _Float16 f16x2;

#if __has_builtin(__builtin_amdgcn_exp2f)
#define EXP2F __builtin_amdgcn_exp2f
#else
#define EXP2F exp2f
#endif

DEVI ushort f2h(float f) {  // RNE scalar convert (v_cvt_f16_f32)
  _Float16 h = (_Float16)f;
  return __builtin_bit_cast(ushort, h);
}

DEVI unsigned pkrtz(float a, float b) {  // v_cvt_pkrtz_f16_f32
  return __builtin_bit_cast(unsigned, __builtin_amdgcn_cvt_pkrtz(a, b));
}

DEVI float dot2acc(unsigned pk, float acc) {
#if __has_builtin(__builtin_amdgcn_fdot2)
  f16x2 one2 = {(_Float16)1.0f, (_Float16)1.0f};
  return __builtin_amdgcn_fdot2(__builtin_bit_cast(f16x2, pk), one2, acc, false);
#else
  f16x2 v = __builtin_bit_cast(f16x2, pk);
  return acc + (float)v[0] + (float)v[1];
#endif
}

DEVI void gload_lds16(const void* g, void* l) {
  typedef const unsigned int GlobU __attribute__((address_space(1)));
  typedef unsigned int LdsU __attribute__((address_space(3)));
  __builtin_amdgcn_global_load_lds((GlobU*)g, (LdsU*)l, 16, 0, 0);
}

// ---------------- fused fp32 -> fp16 cast of x and context ----------------
__global__ __launch_bounds__(256) void cast_f16_kernel(
    const float4* __restrict__ x, const float4* __restrict__ ctx,
    ushort4* __restrict__ xo, ushort4* __restrict__ co) {
  int i = blockIdx.x * 256 + threadIdx.x;
  const float4* src;
  ushort4* dst;
  int j;
  if (i < 2097152) { src = x; dst = xo; j = i; }
  else             { src = ctx; dst = co; j = i - 2097152; }
  float4 v = src[j];
  ushort4 o;
  o.x = f2h(v.x); o.y = f2h(v.y); o.z = f2h(v.z); o.w = f2h(v.w);
  dst[j] = o;
}

// ---------------- fused transpose+cast of the 3 weights (all R=1024 rows) ----------------
__global__ __launch_bounds__(256) void transpose_cast_kernel(
    const float* __restrict__ Wq, const float* __restrict__ Wkv,
    const float* __restrict__ Wo, ushort* __restrict__ WqT,
    ushort* __restrict__ WkvT, ushort* __restrict__ WoT) {
  __shared__ ushort tile[64][65];
  int bx = blockIdx.x;
  const float* in; ushort* out; int C, cb;
  if (bx < 16)      { in = Wq;  out = WqT;  C = 1024; cb = bx * 64; }
  else if (bx < 48) { in = Wkv; out = WkvT; C = 2048; cb = (bx - 16) * 64; }
  else              { in = Wo;  out = WoT;  C = 1024; cb = (bx - 48) * 64; }
  const int R = 1024;
  int rb = blockIdx.y * 64;
  int t = threadIdx.x;
  int c4 = (t & 15) * 4, r0 = t >> 4;
#pragma unroll
  for (int i = 0; i < 4; i++) {
    int r = r0 + i * 16;
    float4 v = *(const float4*)(in + (size_t)(rb + r) * C + cb + c4);
    tile[r][c4 + 0] = f2h(v.x);
    tile[r][c4 + 1] = f2h(v.y);
    tile[r][c4 + 2] = f2h(v.z);
    tile[r][c4 + 3] = f2h(v.w);
  }
  __syncthreads();
#pragma unroll
  for (int i = 0; i < 4; i++) {
    int rr = r0 + i * 16;
    ushort4 o;
    o.x = tile[c4 + 0][rr]; o.y = tile[c4 + 1][rr];
    o.z = tile[c4 + 2][rr]; o.w = tile[c4 + 3][rr];
    *(ushort4*)(out + (size_t)(cb + rr) * R + rb + c4) = o;
  }
}

// ---------------- dbuf fp16 GEMM core ----------------
// As/Bs are 2x (128x32) fp16 buffers (8KB each half). Pipeline: prologue loads
// tiles 0,1; in-loop s_waitcnt vmcnt(4) waits own tile's 4 loads, keeps next
// tile's 4 in flight across the raw s_barrier; refill after compute barrier.
// In-loop VMEM = tile loads ONLY (4 per thread per tile) so vmcnt math is exact.
DEVI void gemm_stage(const ushort* __restrict__ A, const ushort* __restrict__ Bt,
                     int K, int rowbase, int colbase, int tid, int wave,
                     ushort* AsC, ushort* BsC, int kk) {
#pragma unroll
  for (int i = 0; i < 2; i++) {
    int f = i * 256 + tid;
    int r = f >> 2;
    int c = (f & 3) ^ (r & 3);
    gload_lds16(A + (size_t)(rowbase + r) * K + (kk + c * 8),
                (char*)AsC + (size_t)(i * 256 + wave * 64) * 16);
    gload_lds16(Bt + (size_t)(colbase + r) * K + (kk + c * 8),
                (char*)BsC + (size_t)(i * 256 + wave * 64) * 16);
  }
}

DEVI void gemm_core(const ushort* __restrict__ A, const ushort* __restrict__ Bt,
                    const int K, int rowbase, int colbase, int tid,
                    ushort* As, ushort* Bs, f32x4 acc[4][4]) {
  const int lane = tid & 63, wave = tid >> 6;
  const int quad = lane >> 4, ln = lane & 15;
  const int wrow = (wave >> 1) * 64, wcol = (wave & 1) * 64;

  gemm_stage(A, Bt, K, rowbase, colbase, tid, wave, As, Bs, 0);
  gemm_stage(A, Bt, K, rowbase, colbase, tid, wave, As + 4096, Bs + 4096, 32);

  for (int k0 = 0; k0 < K; k0 += 32) {
    const int cur = (k0 >> 5) & 1;
    ushort* AsC = As + cur * 4096;
    ushort* BsC = Bs + cur * 4096;

    if (k0 + 32 < K) asm volatile("s_waitcnt vmcnt(4)" ::: "memory");
    else             asm volatile("s_waitcnt vmcnt(0)" ::: "memory");
    asm volatile("s_barrier" ::: "memory");

    f16x8 a[4], b[4];
#pragma unroll
    for (int mt = 0; mt < 4; mt++) {
      int r = wrow + mt * 16 + ln;
      a[mt] = *(const f16x8*)(AsC + ((size_t)r * 4 + (quad ^ (r & 3))) * 8);
    }
#pragma unroll
    for (int nt = 0; nt < 4; nt++) {
      int r = wcol + nt * 16 + ln;
      b[nt] = *(const f16x8*)(BsC + ((size_t)r * 4 + (quad ^ (r & 3))) * 8);
    }
#pragma unroll
    for (int mt = 0; mt < 4; mt++)
#pragma unroll
      for (int nt = 0; nt < 4; nt++)
        acc[mt][nt] = __builtin_amdgcn_mfma_f32_16x16x32_f16(a[mt], b[nt], acc[mt][nt], 0, 0, 0);

    asm volatile("s_barrier" ::: "memory");
    if (k0 + 64 < K)
      gemm_stage(A, Bt, K, rowbase, colbase, tid, wave, AsC, BsC, k0 + 64);
  }
}

// ---------------- fused Q + KV projection GEMM ----------------
// grid (64 rows, 24 coltiles): xcd = rowtile%8 -> A row-block stays in one XCD's L2
// Q stored TRANSPOSED [b][h][d][n] (like V) for packed epilogue writes.
__global__ __launch_bounds__(256, 3) void qkv_gemm(
    const ushort* __restrict__ xb, const ushort* __restrict__ cb,
    const ushort* __restrict__ WqT, const ushort* __restrict__ WkvT,
    ushort* __restrict__ Qo, ushort* __restrict__ Ko, ushort* __restrict__ Vo) {
  __shared__ ushort As[2 * 128 * 32];
  __shared__ ushort Bs[2 * 128 * 32];
  const int tid = threadIdx.x;
  const int lane = tid & 63, wave = tid >> 6;
  const int quad = lane >> 4, ln = lane & 15;
  const int cy = blockIdx.y;
  const bool isQ = cy < 8;
  const int colbase = (isQ ? cy : cy - 8) * 128;
  const int rowbase = blockIdx.x * 128;
  const int wrow = (wave >> 1) * 64, wcol = (wave & 1) * 64;
  f32x4 acc[4][4] = {};
  gemm_core(isQ ? xb : cb, isQ ? WqT : WkvT, 1024, rowbase, colbase, tid, As, Bs, acc);

  if (isQ) {
    const float qs = 0.18033688011112042f;  // 1/8 * log2(e)
#pragma unroll
    for (int nt = 0; nt < 4; nt++) {
      int col = colbase + wcol + nt * 16 + ln;
      int h = col >> 6, d = col & 63;
#pragma unroll
      for (int mt = 0; mt < 4; mt++) {
        int row = rowbase + wrow + mt * 16 + quad * 4;
        int bb = row >> 11, n = row & 2047;
        uint2 pv;
        pv.x = pkrtz(acc[mt][nt][0] * qs, acc[mt][nt][1] * qs);
        pv.y = pkrtz(acc[mt][nt][2] * qs, acc[mt][nt][3] * qs);
        *(uint2*)(Qo + (((size_t)bb * 16 + h) * 64 + d) * 2048 + n) = pv;
      }
    }
  } else {
    bool isK = (colbase < 1024);
#pragma unroll
    for (int nt = 0; nt < 4; nt++) {
      int col = colbase + wcol + nt * 16 + ln;
#pragma unroll
      for (int mt = 0; mt < 4; mt++) {
        int row = rowbase + wrow + mt * 16 + quad * 4;
        int bb = row >> 11, m = row & 2047;
        if (isK) {
          int h = col >> 6, d = col & 63;
#pragma unroll
          for (int r = 0; r < 4; r++)
            Ko[(((size_t)bb * 16 + h) * 2048 + (m + r)) * 64 + d] = f2h(acc[mt][nt][r]);
        } else {
          int c2 = col - 1024;
          int h = c2 >> 6, d = c2 & 63;
          uint2 pv;
          pv.x = pkrtz(acc[mt][nt][0], acc[mt][nt][1]);
          pv.y = pkrtz(acc[mt][nt][2], acc[mt][nt][3]);
          *(uint2*)(Vo + (((size_t)bb * 16 + h) * 64 + d) * 2048 + m) = pv;
        }
      }
    }
  }
}

// ---------------- out projection: fp32 [M][N] = A @ WoT^T + bias ----------------
__global__ __launch_bounds__(256, 3) void out_gemm(
    const ushort* __restrict__ A, const ushort* __restrict__ Bt,
    float* __restrict__ C, const float* __restrict__ bias) {
  __shared__ ushort As[2 * 128 * 32];
  __shared__ ushort Bs[2 * 128 * 32];
  const int tid = threadIdx.x;
  const int lane = tid & 63, wave = tid >> 6;
  const int quad = lane >> 4, ln = lane & 15;
  const int colbase = blockIdx.y * 128, rowbase = blockIdx.x * 128;
  const int wrow = (wave >> 1) * 64, wcol = (wave & 1) * 64;
  f32x4 acc[4][4] = {};
  gemm_core(A, Bt, 1024, rowbase, colbase, tid, As, Bs, acc);
#pragma unroll
  for (int nt = 0; nt < 4; nt++) {
    int col = colbase + wcol + nt * 16 + ln;
    float bv = bias[col];
#pragma unroll
    for (int mt = 0; mt < 4; mt++) {
      int row = rowbase + wrow + mt * 16 + quad * 4;
#pragma unroll
      for (int r = 0; r < 4; r++)
        C[(size_t)(row + r) * 1024 + col] = acc[mt][nt][r] + bv;
    }
  }
}

// ---------------- flash attention: 8 waves/block, 32 q/wave, dbuf prefetch ----------------
// S^T = K @ Q^T; Q^T layout [b][h][d][n], pre-scaled by 0.125*log2e.
// P staged in B-fragment order: writer puts each packed uint2 exactly where the
// consuming lane's 16B read expects it -> conflict-free LDS both directions.
__global__ __launch_bounds__(512, 4) void attn_kernel(
    const ushort* __restrict__ QT, const ushort* __restrict__ K,
    const ushort* __restrict__ VT, const float* __restrict__ xmask,
    const float* __restrict__ cmask, ushort* __restrict__ O) {
  __shared__ ushort Ks[2][64 * 64];
  __shared__ ushort Vs[2][64 * 64];
  __shared__ ushort Ps[8 * 2048];  // per-wave 4KB: [qt][kc][quad'][ln] 16B frags
  __shared__ float CMB[2048];      // (cmask-1)*3e4 bias, whole context row
  const int tid = threadIdx.x, lane = tid & 63, wave = tid >> 6;  // wave 0..7
  const int quad = lane >> 4, ln = lane & 15;
  const int bid = blockIdx.x;
  const int qb = bid >> 6, bh6 = bid & 63, h = bh6 & 15, b = bh6 >> 4;
  const size_t bh = (size_t)b * 16 + h;
  const ushort* QTbh = QT + bh * (64 * 2048);
  const ushort* Kbh = K + bh * (2048 * 64);
  const ushort* Vbh = VT + bh * (64 * 2048);
  const int q0 = qb * 256 + wave * 32;

  // one-time: stage mask bias into LDS (0 valid / -3e4 masked)
  {
    float4 c0 = *(const float4*)(cmask + b * 2048 + tid * 4);
    float4 b0;
    b0.x = fmaf(c0.x, 3.0e4f, -3.0e4f); b0.y = fmaf(c0.y, 3.0e4f, -3.0e4f);
    b0.z = fmaf(c0.z, 3.0e4f, -3.0e4f); b0.w = fmaf(c0.w, 3.0e4f, -3.0e4f);
    *(float4*)(CMB + tid * 4) = b0;
  }

  // Q fragments from Q^T (one-time scalar loads; B-operand: n=q=ln, k=d=quad*8+j+32*kc)
  f16x8 qf[2][2];
#pragma unroll
  for (int qt = 0; qt < 2; qt++)
#pragma unroll
    for (int kc = 0; kc < 2; kc++) {
      int q = q0 + qt * 16 + ln;
#pragma unroll
      for (int j = 0; j < 8; j++)
        qf[qt][kc][j] = __builtin_bit_cast(_Float16,
            (unsigned short)QTbh[(size_t)(kc * 32 + quad * 8 + j) * 2048 + q]);
    }

  float xm[2];
#pragma unroll
  for (int qt = 0; qt < 2; qt++) xm[qt] = xmask[b * 2048 + q0 + qt * 16 + ln];

  __syncthreads();  // CMB staged; also drains all scalar VMEM (vmcnt clean for pipeline)

  // prologue: prefetch tiles 0 and 1 (1 K-load + 1 V-load per thread per tile)
  {
    int r = tid >> 3;
    int c = (tid & 7) ^ (r & 7);
#pragma unroll
    for (int t = 0; t < 2; t++) {
      gload_lds16(Kbh + (size_t)(t * 64 + r) * 64 + c * 8, (char*)Ks[t] + (size_t)tid * 16);
      gload_lds16(Vbh + (size_t)r * 2048 + (t * 64 + c * 8), (char*)Vs[t] + (size_t)tid * 16);
    }
  }

  f32x4 o[4][2] = {};  // o[dt][qt]: rows d = dt*16+quad*4+r, col q = ln
  float lpart[2] = {0.f, 0.f};  // per-lane partial row sums (reduced once at end)

  for (int kb = 0; kb < 32; kb++) {
    const int cur = kb & 1;
    const int m0 = kb * 64;
    const ushort* KsC = Ks[cur];
    const ushort* VsC = Vs[cur];

    // tile kb ready (own 2 loads done; kb+1's 2 stay in flight), then sync
    if (kb < 31) asm volatile("s_waitcnt vmcnt(2)" ::: "memory");
    else         asm volatile("s_waitcnt vmcnt(0)" ::: "memory");
    asm volatile("s_barrier" ::: "memory");

    // mask bias from LDS (broadcast reads)
    f32x4 bias4[4];
#pragma unroll
    for (int kt = 0; kt < 4; kt++)
      bias4[kt] = *(const f32x4*)(CMB + m0 + kt * 16 + quad * 4);

    // S^T: s[kt][qt], rows = keys (kt*16+quad*4+reg), col = q (ln); C-init = mask bias
    f32x4 s[4][2];
#pragma unroll
    for (int kt = 0; kt < 4; kt++)
#pragma unroll
      for (int qt = 0; qt < 2; qt++) s[kt][qt] = bias4[kt];
#pragma unroll
    for (int kc = 0; kc < 2; kc++) {
#pragma unroll
      for (int kt = 0; kt < 4; kt++) {
        int r = kt * 16 + ln;
        f16x8 ka = *(const f16x8*)(KsC + ((size_t)r * 8 + ((kc * 4 + quad) ^ (r & 7))) * 8);
#pragma unroll
        for (int qt = 0; qt < 2; qt++)
          s[kt][qt] = __builtin_amdgcn_mfma_f32_16x16x32_f16(ka, qf[qt][kc], s[kt][qt], 0, 0, 0);
      }
    }

    // split-P: per 32-key half: exp2 -> pack -> Ps (B-frag order) -> PV MFMA
#pragma unroll
    for (int kc = 0; kc < 2; kc++) {
#pragma unroll
      for (int qt = 0; qt < 2; qt++) {
        ushort* pb = Ps + wave * 2048 + (qt * 2 + kc) * 512;
#pragma unroll
        for (int t = 0; t < 2; t++) {
          int kt = kc * 2 + t;
          float p0 = EXP2F(s[kt][qt][0]);
          float p1 = EXP2F(s[kt][qt][1]);
          float p2 = EXP2F(s[kt][qt][2]);
          float p3 = EXP2F(s[kt][qt][3]);
          uint2 pv;
          pv.x = pkrtz(p0, p1);
          pv.y = pkrtz(p2, p3);
          lpart[qt] = dot2acc(pv.x, lpart[qt]);
          lpart[qt] = dot2acc(pv.y, lpart[qt]);
          // keyh = t*16+quad*4+r -> block quad' = t*2+(quad>>1), 8B half = quad&1
          *(uint2*)(pb + (t * 2 + (quad >> 1)) * 128 + ln * 8 + (quad & 1) * 4) = pv;
        }
      }
      // PV half: o[dt][qt] += V^T(frag A, keys kc*32..) @ P^T(frag B)
      f16x8 pf[2];
#pragma unroll
      for (int qt = 0; qt < 2; qt++)
        pf[qt] = *(const f16x8*)(Ps + wave * 2048 + (qt * 2 + kc) * 512 + quad * 128 + ln * 8);
#pragma unroll
      for (int dt = 0; dt < 4; dt++) {
        int r = dt * 16 + ln;
        f16x8 va = *(const f16x8*)(VsC + ((size_t)r * 8 + ((kc * 4 + quad) ^ (r & 7))) * 8);
#pragma unroll
        for (int qt = 0; qt < 2; qt++)
          o[dt][qt] = __builtin_amdgcn_mfma_f32_16x16x32_f16(va, pf[qt], o[dt][qt], 0, 0, 0);
      }
    }

    // all waves done reading buf[cur]; refill it with tile kb+2
    asm volatile("s_barrier" ::: "memory");
    if (kb < 30) {
      const int m2 = m0 + 128;
      int r = tid >> 3;
      int c = (tid & 7) ^ (r & 7);
      gload_lds16(Kbh + (size_t)(m2 + r) * 64 + c * 8, (char*)Ks[cur] + (size_t)tid * 16);
      gload_lds16(Vbh + (size_t)r * 2048 + (m2 + c * 8), (char*)Vs[cur] + (size_t)tid * 16);
    }
  }

  // normalize + store O [b][n][h*64+d]
#pragma unroll
  for (int qt = 0; qt < 2; qt++) {
    float l = lpart[qt];
    l += __shfl_xor(l, 16, 64);
    l += __shfl_xor(l, 32, 64);
    float inv = (xm[qt] != 0.f && l > 0.f) ? (1.f / l) : 0.f;
    int n = q0 + qt * 16 + ln;
    ushort* ob = O + ((size_t)(b * 2048 + n) * 16 + h) * 64;
#pragma unroll
    for (int dt = 0; dt < 4; dt++) {
      uint2 pv;
      pv.x = pkrtz(o[dt][qt][0] * inv, o[dt][qt][1] * inv);
      pv.y = pkrtz(o[dt][qt][2] * inv, o[dt][qt][3] * inv);
      *(uint2*)(ob + dt * 16 + quad * 4) = pv;
    }
  }
}

// ---------------- host launcher ----------------
extern "C" void kernel_launch(void* const* d_in, const int* in_sizes, int n_in,
                              void* d_out, int out_size, void* d_ws, size_t ws_size,
                              hipStream_t stream) {
  const float* x   = (const float*)d_in[0];
  const float* ctx = (const float*)d_in[1];
  const float* xm  = (const float*)d_in[2];
  const float* cm  = (const float*)d_in[3];
  const float* Wq  = (const float*)d_in[4];
  const float* Wkv = (const float*)d_in[5];
  const float* Wo  = (const float*)d_in[6];
  const float* bo  = (const float*)d_in[7];

  char* ws = (char*)d_ws;
  const size_t MB = 1024 * 1024;
  ushort* xb   = (ushort*)(ws + 0);         // 16MB (x fp16; reused as O after QKV GEMM)
  ushort* cb   = (ushort*)(ws + 16 * MB);   // 16MB (context fp16)
  ushort* WqT  = (ushort*)(ws + 32 * MB);   // 2MB
  ushort* WkvT = (ushort*)(ws + 34 * MB);   // 4MB
  ushort* WoT  = (ushort*)(ws + 38 * MB);   // 2MB
  ushort* QTb  = (ushort*)(ws + 40 * MB);   // 16MB (Q transposed [b][h][d][n])
  ushort* Kb   = (ushort*)(ws + 56 * MB);   // 16MB
  ushort* VTb  = (ushort*)(ws + 72 * MB);   // 16MB
  ushort* Ob   = xb;                        // alias: x fp16 dead after QKV GEMM

  cast_f16_kernel<<<16384, 256, 0, stream>>>((const float4*)x, (const float4*)ctx,
                                             (ushort4*)xb, (ushort4*)cb);
  transpose_cast_kernel<<<dim3(64, 16), 256, 0, stream>>>(Wq, Wkv, Wo, WqT, WkvT, WoT);
  qkv_gemm<<<dim3(64, 24), 256, 0, stream>>>(xb, cb, WqT, WkvT, QTb, Kb, VTb);
  attn_kernel<<<512, 512, 0, stream>>>(QTb, Kb, VTb, xm, cm, Ob);
  out_gemm<<<dim3(64, 8), 256, 0, stream>>>(Ob, WoT, (float*)d_out, bo);
}